// Round 1
// baseline (2301.843 us; speedup 1.0000x reference)
//
#include <hip/hip_runtime.h>
#include <math.h>

#define DD    512
#define NN    32768      // B*L nodes
#define EE    262144     // edges (without self loops)

// ---------------- degree kernels ----------------
__global__ void k_deg_init(float* __restrict__ deg) {
    int i = blockIdx.x * 256 + threadIdx.x;
    if (i < NN) deg[i] = 1.0f;                 // self loop
}

__global__ void k_deg_edges(const int* __restrict__ dst, float* __restrict__ deg) {
    int e = blockIdx.x * 256 + threadIdx.x;
    if (e < EE) atomicAdd(&deg[dst[e]], 1.0f);
}

__global__ void k_dinv(float* __restrict__ deg) {
    int i = blockIdx.x * 256 + threadIdx.x;
    if (i < NN) deg[i] = rsqrtf(deg[i]);       // in place: deg -> deg^{-1/2}
}

// ---------------- fp32 tiled GEMM, fused epilogues ----------------
// MODE 1: C = PReLU(BN(A@B + b1))          (node MLP)
// MODE 2: C = (A@B) * dinv[row]            (xw scaled by src-side dinv)
template <int MODE>
__global__ __launch_bounds__(256) void k_gemm(
    const float* __restrict__ A,   // [NN, DD]
    const float* __restrict__ Bm,  // [DD, DD]
    float* __restrict__ C,         // [NN, DD]
    const float* __restrict__ bias,   // b1 (MODE1) or nullptr
    const float* __restrict__ gamma, const float* __restrict__ beta,
    const float* __restrict__ mean, const float* __restrict__ var,
    const float* __restrict__ alpha,  // scalar ptr (MODE1)
    const float* __restrict__ dinv)   // (MODE2)
{
    __shared__ float As[16][65];   // [k][m], +1 pad
    __shared__ float Bs[16][64];   // [k][n]

    const int m0 = blockIdx.x * 64;
    const int n0 = blockIdx.y * 64;
    const int t  = threadIdx.x;
    const int tx = t & 15;         // n micro-tile
    const int ty = t >> 4;         // m micro-tile
    const int lr = t >> 2;         // A-load row 0..63
    const int lq = t & 3;          // A-load quad 0..3

    float acc[4][4] = {};

    for (int k0 = 0; k0 < DD; k0 += 16) {
        __syncthreads();
        // A tile 64x16 -> transposed into As[k][m]
        float4 av = *(const float4*)(A + (size_t)(m0 + lr) * DD + k0 + lq * 4);
        As[lq * 4 + 0][lr] = av.x;
        As[lq * 4 + 1][lr] = av.y;
        As[lq * 4 + 2][lr] = av.z;
        As[lq * 4 + 3][lr] = av.w;
        // B tile 16x64
        float4 bv = *(const float4*)(Bm + (size_t)(k0 + (t >> 4)) * DD + n0 + (t & 15) * 4);
        *(float4*)&Bs[t >> 4][(t & 15) * 4] = bv;
        __syncthreads();

#pragma unroll
        for (int k = 0; k < 16; ++k) {
            float a0 = As[k][ty * 4 + 0];
            float a1 = As[k][ty * 4 + 1];
            float a2 = As[k][ty * 4 + 2];
            float a3 = As[k][ty * 4 + 3];
            float4 b = *(float4*)&Bs[k][tx * 4];
            acc[0][0] += a0 * b.x; acc[0][1] += a0 * b.y; acc[0][2] += a0 * b.z; acc[0][3] += a0 * b.w;
            acc[1][0] += a1 * b.x; acc[1][1] += a1 * b.y; acc[1][2] += a1 * b.z; acc[1][3] += a1 * b.w;
            acc[2][0] += a2 * b.x; acc[2][1] += a2 * b.y; acc[2][2] += a2 * b.z; acc[2][3] += a2 * b.w;
            acc[3][0] += a3 * b.x; acc[3][1] += a3 * b.y; acc[3][2] += a3 * b.z; acc[3][3] += a3 * b.w;
        }
    }

    // epilogue + store (float4 per row)
    float a1s = (MODE == 1) ? alpha[0] : 0.0f;
#pragma unroll
    for (int i = 0; i < 4; ++i) {
        int m = m0 + ty * 4 + i;
        int n = n0 + tx * 4;
        float4 v;
        float* vp = (float*)&v;
#pragma unroll
        for (int j = 0; j < 4; ++j) {
            float x = acc[i][j];
            int nc = n + j;
            if (MODE == 1) {
                x += bias[nc];
                x = (x - mean[nc]) * rsqrtf(var[nc] + 1e-5f) * gamma[nc] + beta[nc];
                x = (x >= 0.0f) ? x : a1s * x;
            } else {
                x *= dinv[m];
            }
            vp[j] = x;
        }
        *(float4*)(C + (size_t)m * DD + n) = v;
    }
}

// ---------------- edge scatter-add ----------------
__global__ __launch_bounds__(256) void k_scatter(
    const int* __restrict__ src, const int* __restrict__ dst,
    const float* __restrict__ xws, float* __restrict__ agg)
{
    int tid = blockIdx.x * 256 + threadIdx.x;   // EE*128 threads, 4 floats each
    int e = tid >> 7;
    int c = (tid & 127) * 4;
    int s = src[e];
    int d = dst[e];
    float4 v = *(const float4*)(xws + (size_t)s * DD + c);
    float* p = agg + (size_t)d * DD + c;
    atomicAdd(p + 0, v.x);
    atomicAdd(p + 1, v.y);
    atomicAdd(p + 2, v.z);
    atomicAdd(p + 3, v.w);
}

// ---------------- final: dinv*agg + bg, PReLU, L2 norm, residual ----------------
__global__ __launch_bounds__(256) void k_final(
    const float* __restrict__ agg, const float* __restrict__ dinv,
    const float* __restrict__ bg, const float* __restrict__ alpha2,
    const float* __restrict__ text, float* __restrict__ out)
{
    int node = blockIdx.x;
    int t = threadIdx.x;
    float di = dinv[node];
    float a2 = alpha2[0];

    float g[2];
    float ss = 0.0f;
#pragma unroll
    for (int j = 0; j < 2; ++j) {
        int d = t + j * 256;
        float v = agg[(size_t)node * DD + d] * di + bg[d];
        v = (v >= 0.0f) ? v : a2 * v;
        g[j] = v;
        ss += v * v;
    }
    // 64-lane wave reduce then cross-wave
#pragma unroll
    for (int off = 32; off > 0; off >>= 1) ss += __shfl_down(ss, off, 64);
    __shared__ float red[4];
    if ((t & 63) == 0) red[t >> 6] = ss;
    __syncthreads();
    float tot = red[0] + red[1] + red[2] + red[3];
    float inv = 1.0f / fmaxf(sqrtf(tot), 1e-12f);
#pragma unroll
    for (int j = 0; j < 2; ++j) {
        int d = t + j * 256;
        out[(size_t)node * DD + d] = g[j] * inv + text[(size_t)node * DD + d];
    }
}

extern "C" void kernel_launch(void* const* d_in, const int* in_sizes, int n_in,
                              void* d_out, int out_size, void* d_ws, size_t ws_size,
                              hipStream_t stream) {
    const float* text   = (const float*)d_in[0];
    const int*   esrc   = (const int*)d_in[1];
    const int*   edst   = (const int*)d_in[2];
    const float* W1     = (const float*)d_in[3];
    const float* b1     = (const float*)d_in[4];
    const float* gamma  = (const float*)d_in[5];
    const float* beta   = (const float*)d_in[6];
    const float* rmean  = (const float*)d_in[7];
    const float* rvar   = (const float*)d_in[8];
    const float* alpha1 = (const float*)d_in[9];
    const float* Wg     = (const float*)d_in[10];
    const float* bg     = (const float*)d_in[11];
    const float* alpha2 = (const float*)d_in[12];
    float* out = (float*)d_out;

    // workspace layout
    char* ws = (char*)d_ws;
    float* dinv = (float*)ws;                                   // NN floats (128 KB)
    float* h    = (float*)(ws + (size_t)131072);                // NN*DD floats (64 MB); reused as agg
    float* xws  = (float*)(ws + (size_t)131072 + (size_t)NN * DD * 4); // NN*DD floats (64 MB)
    float* agg  = h;

    // 1) degrees -> dinv
    k_deg_init<<<NN / 256, 256, 0, stream>>>(dinv);
    k_deg_edges<<<EE / 256, 256, 0, stream>>>(edst, dinv);
    k_dinv<<<NN / 256, 256, 0, stream>>>(dinv);

    // 2) h = PReLU(BN(text@W1 + b1))
    dim3 g1(NN / 64, DD / 64);
    k_gemm<1><<<g1, 256, 0, stream>>>(text, W1, h, b1, gamma, beta, rmean, rvar, alpha1, nullptr);

    // 3) xws = (h@Wg) * dinv[row]
    k_gemm<2><<<g1, 256, 0, stream>>>(h, Wg, xws, nullptr, nullptr, nullptr, nullptr, nullptr, nullptr, dinv);

    // 4) agg = xws (self loop), then scatter-add edge messages
    hipMemcpyAsync(agg, xws, (size_t)NN * DD * 4, hipMemcpyDeviceToDevice, stream);
    k_scatter<<<(EE * 128) / 256, 256, 0, stream>>>(esrc, edst, xws, agg);

    // 5) final: norm + residual
    k_final<<<NN, 256, 0, stream>>>(agg, dinv, bg, alpha2, text, out);
}

// Round 2
// 627.022 us; speedup vs baseline: 3.6711x; 3.6711x over previous
//
#include <hip/hip_runtime.h>
#include <math.h>

#define DD    512
#define NN    32768      // B*L nodes
#define EE    262144     // edges (without self loops)

// ---------------- CSR build ----------------
__global__ void k_zero(int* __restrict__ cnt) {
    int i = blockIdx.x * 256 + threadIdx.x;
    if (i < NN) cnt[i] = 0;
}

__global__ void k_count(const int* __restrict__ dst, int* __restrict__ cnt) {
    int e = blockIdx.x * 256 + threadIdx.x;
    if (e < EE) atomicAdd(&cnt[dst[e]], 1);
}

// single block: exclusive scan of cnt[NN] -> offs[NN+1]; also cursor copy + dinv
__global__ __launch_bounds__(1024) void k_scan(
    const int* __restrict__ cnt, int* __restrict__ offs,
    int* __restrict__ cursor, float* __restrict__ dinv)
{
    __shared__ int part[1024];
    int t = threadIdx.x;
    int base = t * 32;
    int local[32];
    int s = 0;
#pragma unroll
    for (int i = 0; i < 32; ++i) { local[i] = s; s += cnt[base + i]; }
    part[t] = s;
    __syncthreads();
    for (int off = 1; off < 1024; off <<= 1) {
        int v = (t >= off) ? part[t - off] : 0;
        __syncthreads();
        part[t] += v;
        __syncthreads();
    }
    int prev = (t == 0) ? 0 : part[t - 1];
#pragma unroll
    for (int i = 0; i < 32; ++i) {
        int o = prev + local[i];
        offs[base + i] = o;
        cursor[base + i] = o;
        dinv[base + i] = rsqrtf((float)cnt[base + i] + 1.0f);
    }
    if (t == 1023) offs[NN] = part[1023];
}

__global__ void k_fill(const int* __restrict__ src, const int* __restrict__ dst,
                       int* __restrict__ cursor, int* __restrict__ csr) {
    int e = blockIdx.x * 256 + threadIdx.x;
    if (e < EE) {
        int d = dst[e];
        int p = atomicAdd(&cursor[d], 1);
        csr[p] = src[e];
    }
}

// ---------------- fp32 tiled GEMM, fused epilogues ----------------
// MODE 1: C = PReLU(BN(A@B + b1))          (node MLP)
// MODE 2: C = (A@B) * dinv[row]            (xw scaled by src-side dinv)
template <int MODE>
__global__ __launch_bounds__(256) void k_gemm(
    const float* __restrict__ A,   // [NN, DD]
    const float* __restrict__ Bm,  // [DD, DD]
    float* __restrict__ C,         // [NN, DD]
    const float* __restrict__ bias,
    const float* __restrict__ gamma, const float* __restrict__ beta,
    const float* __restrict__ mean, const float* __restrict__ var,
    const float* __restrict__ alpha,
    const float* __restrict__ dinv)
{
    __shared__ float As[16][65];   // [k][m], +1 pad
    __shared__ float Bs[16][64];   // [k][n]

    const int m0 = blockIdx.x * 64;
    const int n0 = blockIdx.y * 64;
    const int t  = threadIdx.x;
    const int tx = t & 15;
    const int ty = t >> 4;
    const int lr = t >> 2;
    const int lq = t & 3;

    float acc[4][4] = {};

    for (int k0 = 0; k0 < DD; k0 += 16) {
        __syncthreads();
        float4 av = *(const float4*)(A + (size_t)(m0 + lr) * DD + k0 + lq * 4);
        As[lq * 4 + 0][lr] = av.x;
        As[lq * 4 + 1][lr] = av.y;
        As[lq * 4 + 2][lr] = av.z;
        As[lq * 4 + 3][lr] = av.w;
        float4 bv = *(const float4*)(Bm + (size_t)(k0 + (t >> 4)) * DD + n0 + (t & 15) * 4);
        *(float4*)&Bs[t >> 4][(t & 15) * 4] = bv;
        __syncthreads();

#pragma unroll
        for (int k = 0; k < 16; ++k) {
            float a0 = As[k][ty * 4 + 0];
            float a1 = As[k][ty * 4 + 1];
            float a2 = As[k][ty * 4 + 2];
            float a3 = As[k][ty * 4 + 3];
            float4 b = *(float4*)&Bs[k][tx * 4];
            acc[0][0] += a0 * b.x; acc[0][1] += a0 * b.y; acc[0][2] += a0 * b.z; acc[0][3] += a0 * b.w;
            acc[1][0] += a1 * b.x; acc[1][1] += a1 * b.y; acc[1][2] += a1 * b.z; acc[1][3] += a1 * b.w;
            acc[2][0] += a2 * b.x; acc[2][1] += a2 * b.y; acc[2][2] += a2 * b.z; acc[2][3] += a2 * b.w;
            acc[3][0] += a3 * b.x; acc[3][1] += a3 * b.y; acc[3][2] += a3 * b.z; acc[3][3] += a3 * b.w;
        }
    }

    float a1s = (MODE == 1) ? alpha[0] : 0.0f;
#pragma unroll
    for (int i = 0; i < 4; ++i) {
        int m = m0 + ty * 4 + i;
        int n = n0 + tx * 4;
        float4 v;
        float* vp = (float*)&v;
#pragma unroll
        for (int j = 0; j < 4; ++j) {
            float x = acc[i][j];
            int nc = n + j;
            if (MODE == 1) {
                x += bias[nc];
                x = (x - mean[nc]) * rsqrtf(var[nc] + 1e-5f) * gamma[nc] + beta[nc];
                x = (x >= 0.0f) ? x : a1s * x;
            } else {
                x *= dinv[m];
            }
            vp[j] = x;
        }
        *(float4*)(C + (size_t)m * DD + n) = v;
    }
}

// ---------------- fused gather + dinv + bias + PReLU + L2 norm + residual ----------------
__global__ __launch_bounds__(256) void k_gather_final(
    const int* __restrict__ offs, const int* __restrict__ csr,
    const float* __restrict__ xws, const float* __restrict__ dinv,
    const float* __restrict__ bg, const float* __restrict__ alpha2,
    const float* __restrict__ text, float* __restrict__ out)
{
    int node = blockIdx.x;
    int t = threadIdx.x;
    int c = t * 2;
    int beg = offs[node], end = offs[node + 1];

    // self loop message
    float2 acc = *(const float2*)(xws + (size_t)node * DD + c);
    for (int e = beg; e < end; ++e) {
        int s = csr[e];
        float2 v = *(const float2*)(xws + (size_t)s * DD + c);
        acc.x += v.x; acc.y += v.y;
    }

    float di = dinv[node];
    float a2 = alpha2[0];
    float g0 = acc.x * di + bg[c];
    float g1 = acc.y * di + bg[c + 1];
    g0 = (g0 >= 0.0f) ? g0 : a2 * g0;
    g1 = (g1 >= 0.0f) ? g1 : a2 * g1;

    float ss = g0 * g0 + g1 * g1;
#pragma unroll
    for (int off = 32; off > 0; off >>= 1) ss += __shfl_down(ss, off, 64);
    __shared__ float red[4];
    if ((t & 63) == 0) red[t >> 6] = ss;
    __syncthreads();
    float tot = red[0] + red[1] + red[2] + red[3];
    float inv = 1.0f / fmaxf(sqrtf(tot), 1e-12f);

    float2 tx = *(const float2*)(text + (size_t)node * DD + c);
    float2 o;
    o.x = g0 * inv + tx.x;
    o.y = g1 * inv + tx.y;
    *(float2*)(out + (size_t)node * DD + c) = o;
}

extern "C" void kernel_launch(void* const* d_in, const int* in_sizes, int n_in,
                              void* d_out, int out_size, void* d_ws, size_t ws_size,
                              hipStream_t stream) {
    const float* text   = (const float*)d_in[0];
    const int*   esrc   = (const int*)d_in[1];
    const int*   edst   = (const int*)d_in[2];
    const float* W1     = (const float*)d_in[3];
    const float* b1     = (const float*)d_in[4];
    const float* gamma  = (const float*)d_in[5];
    const float* beta   = (const float*)d_in[6];
    const float* rmean  = (const float*)d_in[7];
    const float* rvar   = (const float*)d_in[8];
    const float* alpha1 = (const float*)d_in[9];
    const float* Wg     = (const float*)d_in[10];
    const float* bg     = (const float*)d_in[11];
    const float* alpha2 = (const float*)d_in[12];
    float* out = (float*)d_out;

    // workspace layout (~129.6 MiB)
    char* ws = (char*)d_ws;
    int*   cnt    = (int*)ws;                       ws += (size_t)NN * 4;       // 128 KB
    int*   offs   = (int*)ws;                       ws += (size_t)(NN + 64) * 4;
    int*   cursor = (int*)ws;                       ws += (size_t)NN * 4;
    float* dinv   = (float*)ws;                     ws += (size_t)NN * 4;
    int*   csr    = (int*)ws;                       ws += (size_t)EE * 4;       // 1 MB
    float* h      = (float*)ws;                     ws += (size_t)NN * DD * 4;  // 64 MB
    float* xws    = (float*)ws;                                                  // 64 MB

    // 1) CSR build + dinv
    k_zero<<<NN / 256, 256, 0, stream>>>(cnt);
    k_count<<<EE / 256, 256, 0, stream>>>(edst, cnt);
    k_scan<<<1, 1024, 0, stream>>>(cnt, offs, cursor, dinv);
    k_fill<<<EE / 256, 256, 0, stream>>>(esrc, edst, cursor, csr);

    // 2) h = PReLU(BN(text@W1 + b1))
    dim3 g1(NN / 64, DD / 64);
    k_gemm<1><<<g1, 256, 0, stream>>>(text, W1, h, b1, gamma, beta, rmean, rvar, alpha1, nullptr);

    // 3) xws = (h@Wg) * dinv[row]
    k_gemm<2><<<g1, 256, 0, stream>>>(h, Wg, xws, nullptr, nullptr, nullptr, nullptr, nullptr, nullptr, dinv);

    // 4) fused gather + epilogue + L2 norm + residual
    k_gather_final<<<NN, 256, 0, stream>>>(offs, csr, xws, dinv, bg, alpha2, text, out);
}

// Round 3
// 219.848 us; speedup vs baseline: 10.4701x; 2.8521x over previous
//
#include <hip/hip_runtime.h>
#include <math.h>

#define DD    512
#define NN    32768      // B*L nodes
#define EE    262144     // edges (without self loops)

typedef float f32x4 __attribute__((ext_vector_type(4)));
typedef __bf16 bf16x8 __attribute__((ext_vector_type(8)));
typedef __bf16 bf16x4 __attribute__((ext_vector_type(4)));

// ---------------- CSR build ----------------
__global__ void k_zero(int* __restrict__ cnt) {
    int i = blockIdx.x * 256 + threadIdx.x;
    if (i < NN) cnt[i] = 0;
}

__global__ void k_count(const int* __restrict__ dst, int* __restrict__ cnt) {
    int e = blockIdx.x * 256 + threadIdx.x;
    if (e < EE) atomicAdd(&cnt[dst[e]], 1);
}

__global__ __launch_bounds__(1024) void k_scan(
    const int* __restrict__ cnt, int* __restrict__ offs,
    int* __restrict__ cursor, float* __restrict__ dinv)
{
    __shared__ int part[1024];
    int t = threadIdx.x;
    int base = t * 32;
    int local[32];
    int s = 0;
#pragma unroll
    for (int i = 0; i < 32; ++i) { local[i] = s; s += cnt[base + i]; }
    part[t] = s;
    __syncthreads();
    for (int off = 1; off < 1024; off <<= 1) {
        int v = (t >= off) ? part[t - off] : 0;
        __syncthreads();
        part[t] += v;
        __syncthreads();
    }
    int prev = (t == 0) ? 0 : part[t - 1];
#pragma unroll
    for (int i = 0; i < 32; ++i) {
        int o = prev + local[i];
        offs[base + i] = o;
        cursor[base + i] = o;
        dinv[base + i] = rsqrtf((float)cnt[base + i] + 1.0f);
    }
    if (t == 1023) offs[NN] = part[1023];
}

__global__ void k_fill(const int* __restrict__ src, const int* __restrict__ dst,
                       int* __restrict__ cursor, int* __restrict__ csr) {
    int e = blockIdx.x * 256 + threadIdx.x;
    if (e < EE) {
        int d = dst[e];
        int p = atomicAdd(&cursor[d], 1);
        csr[p] = src[e];
    }
}

// ---------------- fp32 -> bf16 convert (text) ----------------
__global__ __launch_bounds__(256) void k_cvt(const float* __restrict__ in, __bf16* __restrict__ out) {
    int i = blockIdx.x * 256 + threadIdx.x;
    float4 v = ((const float4*)in)[i];
    bf16x4 o;
    o[0] = (__bf16)v.x; o[1] = (__bf16)v.y; o[2] = (__bf16)v.z; o[3] = (__bf16)v.w;
    *(bf16x4*)(out + (size_t)i * 4) = o;
}

// ---------------- weight transpose + convert: Wt[n][k] = (bf16)W[k][n] ----------------
__global__ __launch_bounds__(256) void k_wt(const float* __restrict__ W1, const float* __restrict__ Wg,
                                            __bf16* __restrict__ W1t, __bf16* __restrict__ Wgt) {
    __shared__ float tile[32][33];
    const float* W = blockIdx.z ? Wg : W1;
    __bf16* Wt = blockIdx.z ? Wgt : W1t;
    int x0 = blockIdx.x * 32;   // n block
    int y0 = blockIdx.y * 32;   // k block
    int tx = threadIdx.x;       // 0..31
    for (int j = threadIdx.y; j < 32; j += 8)
        tile[j][tx] = W[(size_t)(y0 + j) * DD + x0 + tx];   // tile[k_local][n_local]
    __syncthreads();
    for (int j = threadIdx.y; j < 32; j += 8)
        Wt[(size_t)(x0 + j) * DD + y0 + tx] = (__bf16)tile[tx][j];
}

// ---------------- bf16 MFMA GEMM, 128x128 tile, BK=32, fused epilogues ----------------
// A: [M,512] bf16 row-major. Bt: [512,512] bf16, [n][k] (transposed weight).
// MODE 1: h_bf16 = PReLU(BN(A@B + b1))
// MODE 2: xws_f32 = (A@B) * dinv[row]
template <int MODE>
__global__ __launch_bounds__(256) void k_gemm_mfma(
    const __bf16* __restrict__ A,
    const __bf16* __restrict__ Bt,
    void* __restrict__ Cout,
    const float* __restrict__ bias,
    const float* __restrict__ gamma, const float* __restrict__ beta,
    const float* __restrict__ mean, const float* __restrict__ var,
    const float* __restrict__ alphap,
    const float* __restrict__ dinv)
{
    // Each tile: [128 rows][32 k] bf16 = 8 KB. Row = 4 chunks of 16B.
    // Swizzle: chunk c of row r stored at slot s = c ^ ((r>>1)&3)  (2-way bank aliasing only)
    __shared__ __bf16 lds[2][128 * 32];

    const int tid  = threadIdx.x;
    const int lane = tid & 63;
    const int w    = tid >> 6;            // wave 0..3
    const int wm   = (w >> 1) * 64;       // wave row offset in tile
    const int wn   = (w & 1) * 64;        // wave col offset in tile
    const int m0   = blockIdx.x * 128;
    const int n0   = blockIdx.y * 128;

    f32x4 acc[4][4] = {};

    for (int k0 = 0; k0 < DD; k0 += 32) {
        __syncthreads();
        // stage A and B tiles via global_load_lds (16B/lane, LDS linear, source pre-swizzled)
#pragma unroll
        for (int rd = 0; rd < 2; ++rd) {
            int cbase = rd * 256 + w * 64;
            int cidx = cbase + lane;
            int r = cidx >> 2, s = cidx & 3;
            int c = s ^ ((r >> 1) & 3);
            const __bf16* ga = A  + (size_t)(m0 + r) * DD + k0 + c * 8;
            const __bf16* gb = Bt + (size_t)(n0 + r) * DD + k0 + c * 8;
            __builtin_amdgcn_global_load_lds(
                (const __attribute__((address_space(1))) unsigned int*)ga,
                (__attribute__((address_space(3))) unsigned int*)(&lds[0][cbase * 8]), 16, 0, 0);
            __builtin_amdgcn_global_load_lds(
                (const __attribute__((address_space(1))) unsigned int*)gb,
                (__attribute__((address_space(3))) unsigned int*)(&lds[1][cbase * 8]), 16, 0, 0);
        }
        __syncthreads();

        bf16x8 af[4], bf[4];
#pragma unroll
        for (int m = 0; m < 4; ++m) {
            int r = wm + m * 16 + (lane & 15);
            int s = (lane >> 4) ^ ((r >> 1) & 3);
            af[m] = *(const bf16x8*)&lds[0][r * 32 + s * 8];
            int q = wn + m * 16 + (lane & 15);
            int sq = (lane >> 4) ^ ((q >> 1) & 3);
            bf[m] = *(const bf16x8*)&lds[1][q * 32 + sq * 8];
        }
#pragma unroll
        for (int m = 0; m < 4; ++m)
#pragma unroll
            for (int n = 0; n < 4; ++n)
                acc[m][n] = __builtin_amdgcn_mfma_f32_16x16x32_bf16(af[m], bf[n], acc[m][n], 0, 0, 0);
    }

    // epilogue: C/D layout col = lane&15, row = (lane>>4)*4 + j
    float alpha = (MODE == 1) ? alphap[0] : 0.0f;
#pragma unroll
    for (int m = 0; m < 4; ++m) {
        int row_base = m0 + wm + m * 16 + ((lane >> 4) << 2);
#pragma unroll
        for (int n = 0; n < 4; ++n) {
            int col = n0 + wn + n * 16 + (lane & 15);
#pragma unroll
            for (int j = 0; j < 4; ++j) {
                int row = row_base + j;
                float x = acc[m][n][j];
                if (MODE == 1) {
                    x += bias[col];
                    x = (x - mean[col]) * rsqrtf(var[col] + 1e-5f) * gamma[col] + beta[col];
                    x = (x >= 0.0f) ? x : alpha * x;
                    ((__bf16*)Cout)[(size_t)row * DD + col] = (__bf16)x;
                } else {
                    x *= dinv[row];
                    ((float*)Cout)[(size_t)row * DD + col] = x;
                }
            }
        }
    }
}

// ---------------- fused gather + dinv + bias + PReLU + L2 norm + residual ----------------
__global__ __launch_bounds__(256) void k_gather_final(
    const int* __restrict__ offs, const int* __restrict__ csr,
    const float* __restrict__ xws, const float* __restrict__ dinv,
    const float* __restrict__ bg, const float* __restrict__ alpha2,
    const float* __restrict__ text, float* __restrict__ out)
{
    int node = blockIdx.x;
    int t = threadIdx.x;
    int c = t * 2;
    int beg = offs[node], end = offs[node + 1];

    float2 acc = *(const float2*)(xws + (size_t)node * DD + c);   // self loop
    for (int e = beg; e < end; ++e) {
        int s = csr[e];
        float2 v = *(const float2*)(xws + (size_t)s * DD + c);
        acc.x += v.x; acc.y += v.y;
    }

    float di = dinv[node];
    float a2 = alpha2[0];
    float g0 = acc.x * di + bg[c];
    float g1 = acc.y * di + bg[c + 1];
    g0 = (g0 >= 0.0f) ? g0 : a2 * g0;
    g1 = (g1 >= 0.0f) ? g1 : a2 * g1;

    float ss = g0 * g0 + g1 * g1;
#pragma unroll
    for (int off = 32; off > 0; off >>= 1) ss += __shfl_down(ss, off, 64);
    __shared__ float red[4];
    if ((t & 63) == 0) red[t >> 6] = ss;
    __syncthreads();
    float tot = red[0] + red[1] + red[2] + red[3];
    float inv = 1.0f / fmaxf(sqrtf(tot), 1e-12f);

    float2 tx = *(const float2*)(text + (size_t)node * DD + c);
    float2 o;
    o.x = g0 * inv + tx.x;
    o.y = g1 * inv + tx.y;
    *(float2*)(out + (size_t)node * DD + c) = o;
}

extern "C" void kernel_launch(void* const* d_in, const int* in_sizes, int n_in,
                              void* d_out, int out_size, void* d_ws, size_t ws_size,
                              hipStream_t stream) {
    const float* text   = (const float*)d_in[0];
    const int*   esrc   = (const int*)d_in[1];
    const int*   edst   = (const int*)d_in[2];
    const float* W1     = (const float*)d_in[3];
    const float* b1     = (const float*)d_in[4];
    const float* gamma  = (const float*)d_in[5];
    const float* beta   = (const float*)d_in[6];
    const float* rmean  = (const float*)d_in[7];
    const float* rvar   = (const float*)d_in[8];
    const float* alpha1 = (const float*)d_in[9];
    const float* Wg     = (const float*)d_in[10];
    const float* bg     = (const float*)d_in[11];
    const float* alpha2 = (const float*)d_in[12];
    float* out = (float*)d_out;

    // workspace layout (~98.5 MiB)
    char* p = (char*)d_ws;
    auto alloc = [&](size_t bytes) { char* r = p; p += (bytes + 255) & ~(size_t)255; return r; };
    int*    cnt    = (int*)alloc((size_t)NN * 4);
    int*    offs   = (int*)alloc((size_t)(NN + 1) * 4);
    int*    cursor = (int*)alloc((size_t)NN * 4);
    float*  dinv   = (float*)alloc((size_t)NN * 4);
    int*    csr    = (int*)alloc((size_t)EE * 4);
    __bf16* W1t    = (__bf16*)alloc((size_t)DD * DD * 2);
    __bf16* Wgt    = (__bf16*)alloc((size_t)DD * DD * 2);
    __bf16* h_bf   = (__bf16*)alloc((size_t)NN * DD * 2);
    float*  xws    = (float*)alloc((size_t)NN * DD * 4);
    __bf16* text_bf = (__bf16*)xws;   // alias: consumed by GEMM1 before GEMM2 writes xws

    // 1) CSR build + dinv
    k_zero<<<NN / 256, 256, 0, stream>>>(cnt);
    k_count<<<EE / 256, 256, 0, stream>>>(edst, cnt);
    k_scan<<<1, 1024, 0, stream>>>(cnt, offs, cursor, dinv);
    k_fill<<<EE / 256, 256, 0, stream>>>(esrc, edst, cursor, csr);

    // 2) convert inputs to bf16
    k_cvt<<<(NN * DD / 4) / 256, 256, 0, stream>>>(text, text_bf);
    k_wt<<<dim3(16, 16, 2), dim3(32, 8), 0, stream>>>(W1, Wg, W1t, Wgt);

    // 3) h = PReLU(BN(text@W1 + b1))   [bf16 out]
    dim3 gg(NN / 128, DD / 128);
    k_gemm_mfma<1><<<gg, 256, 0, stream>>>(text_bf, W1t, h_bf, b1, gamma, beta, rmean, rvar, alpha1, nullptr);

    // 4) xws = (h@Wg) * dinv[row]     [fp32 out]
    k_gemm_mfma<2><<<gg, 256, 0, stream>>>(h_bf, Wgt, xws, nullptr, nullptr, nullptr, nullptr, nullptr, nullptr, dinv);

    // 5) fused gather + epilogue + L2 norm + residual
    k_gather_final<<<NN, 256, 0, stream>>>(offs, csr, xws, dinv, bg, alpha2, text, out);
}

// Round 4
// 173.220 us; speedup vs baseline: 13.2885x; 1.2692x over previous
//
#include <hip/hip_runtime.h>
#include <math.h>

#define DD    512
#define NN    32768      // B*L nodes
#define EE    262144     // edges (without self loops)

typedef float f32x4 __attribute__((ext_vector_type(4)));
typedef __bf16 bf16x8 __attribute__((ext_vector_type(8)));
typedef __bf16 bf16x4 __attribute__((ext_vector_type(4)));

// ---------------- CSR build ----------------
__global__ void k_zero(int* __restrict__ cnt) {
    int i = blockIdx.x * 256 + threadIdx.x;
    if (i < NN) cnt[i] = 0;
}

__global__ void k_count(const int* __restrict__ dst, int* __restrict__ cnt) {
    int e = blockIdx.x * 256 + threadIdx.x;
    if (e < EE) atomicAdd(&cnt[dst[e]], 1);
}

__global__ __launch_bounds__(1024) void k_scan(
    const int* __restrict__ cnt, int* __restrict__ offs,
    int* __restrict__ cursor, float* __restrict__ dinv)
{
    __shared__ int part[1024];
    int t = threadIdx.x;
    int base = t * 32;
    int local[32];
    int s = 0;
#pragma unroll
    for (int i = 0; i < 32; ++i) { local[i] = s; s += cnt[base + i]; }
    part[t] = s;
    __syncthreads();
    for (int off = 1; off < 1024; off <<= 1) {
        int v = (t >= off) ? part[t - off] : 0;
        __syncthreads();
        part[t] += v;
        __syncthreads();
    }
    int prev = (t == 0) ? 0 : part[t - 1];
#pragma unroll
    for (int i = 0; i < 32; ++i) {
        int o = prev + local[i];
        offs[base + i] = o;
        cursor[base + i] = o;
        dinv[base + i] = rsqrtf((float)cnt[base + i] + 1.0f);
    }
    if (t == 1023) offs[NN] = part[1023];
}

__global__ void k_fill(const int* __restrict__ src, const int* __restrict__ dst,
                       int* __restrict__ cursor, int* __restrict__ csr) {
    int e = blockIdx.x * 256 + threadIdx.x;
    if (e < EE) {
        int d = dst[e];
        int p = atomicAdd(&cursor[d], 1);
        csr[p] = src[e];
    }
}

// ---------------- fp32 -> bf16 convert (text) ----------------
__global__ __launch_bounds__(256) void k_cvt(const float* __restrict__ in, __bf16* __restrict__ out) {
    int i = blockIdx.x * 256 + threadIdx.x;
    float4 v = ((const float4*)in)[i];
    bf16x4 o;
    o[0] = (__bf16)v.x; o[1] = (__bf16)v.y; o[2] = (__bf16)v.z; o[3] = (__bf16)v.w;
    *(bf16x4*)(out + (size_t)i * 4) = o;
}

// ---------------- weight transpose + convert: Wt[n][k] = (bf16)W[k][n] ----------------
__global__ __launch_bounds__(256) void k_wt(const float* __restrict__ W1, const float* __restrict__ Wg,
                                            __bf16* __restrict__ W1t, __bf16* __restrict__ Wgt) {
    __shared__ float tile[32][33];
    const float* W = blockIdx.z ? Wg : W1;
    __bf16* Wt = blockIdx.z ? Wgt : W1t;
    int x0 = blockIdx.x * 32;   // n block
    int y0 = blockIdx.y * 32;   // k block
    int tx = threadIdx.x;       // 0..31
    for (int j = threadIdx.y; j < 32; j += 8)
        tile[j][tx] = W[(size_t)(y0 + j) * DD + x0 + tx];
    __syncthreads();
    for (int j = threadIdx.y; j < 32; j += 8)
        Wt[(size_t)(x0 + j) * DD + y0 + tx] = (__bf16)tile[tx][j];
}

// ---------------- bf16 MFMA GEMM, 128x128 tile, BK=32, fused epilogues ----------------
// MODE 1: h_bf16 = PReLU(BN(A@B + b1))
// MODE 2: xws_bf16 = (A@B) * dinv[row]
template <int MODE>
__global__ __launch_bounds__(256) void k_gemm_mfma(
    const __bf16* __restrict__ A,
    const __bf16* __restrict__ Bt,
    __bf16* __restrict__ Cout,
    const float* __restrict__ bias,
    const float* __restrict__ gamma, const float* __restrict__ beta,
    const float* __restrict__ mean, const float* __restrict__ var,
    const float* __restrict__ alphap,
    const float* __restrict__ dinv)
{
    __shared__ __bf16 lds[2][128 * 32];

    const int tid  = threadIdx.x;
    const int lane = tid & 63;
    const int w    = tid >> 6;
    const int wm   = (w >> 1) * 64;
    const int wn   = (w & 1) * 64;
    const int m0   = blockIdx.x * 128;
    const int n0   = blockIdx.y * 128;

    f32x4 acc[4][4] = {};

    for (int k0 = 0; k0 < DD; k0 += 32) {
        __syncthreads();
#pragma unroll
        for (int rd = 0; rd < 2; ++rd) {
            int cbase = rd * 256 + w * 64;
            int cidx = cbase + lane;
            int r = cidx >> 2, s = cidx & 3;
            int c = s ^ ((r >> 1) & 3);
            const __bf16* ga = A  + (size_t)(m0 + r) * DD + k0 + c * 8;
            const __bf16* gb = Bt + (size_t)(n0 + r) * DD + k0 + c * 8;
            __builtin_amdgcn_global_load_lds(
                (const __attribute__((address_space(1))) unsigned int*)ga,
                (__attribute__((address_space(3))) unsigned int*)(&lds[0][cbase * 8]), 16, 0, 0);
            __builtin_amdgcn_global_load_lds(
                (const __attribute__((address_space(1))) unsigned int*)gb,
                (__attribute__((address_space(3))) unsigned int*)(&lds[1][cbase * 8]), 16, 0, 0);
        }
        __syncthreads();

        bf16x8 af[4], bf[4];
#pragma unroll
        for (int m = 0; m < 4; ++m) {
            int r = wm + m * 16 + (lane & 15);
            int s = (lane >> 4) ^ ((r >> 1) & 3);
            af[m] = *(const bf16x8*)&lds[0][r * 32 + s * 8];
            int q = wn + m * 16 + (lane & 15);
            int sq = (lane >> 4) ^ ((q >> 1) & 3);
            bf[m] = *(const bf16x8*)&lds[1][q * 32 + sq * 8];
        }
#pragma unroll
        for (int m = 0; m < 4; ++m)
#pragma unroll
            for (int n = 0; n < 4; ++n)
                acc[m][n] = __builtin_amdgcn_mfma_f32_16x16x32_bf16(af[m], bf[n], acc[m][n], 0, 0, 0);
    }

    float alpha = (MODE == 1) ? alphap[0] : 0.0f;
#pragma unroll
    for (int m = 0; m < 4; ++m) {
        int row_base = m0 + wm + m * 16 + ((lane >> 4) << 2);
#pragma unroll
        for (int n = 0; n < 4; ++n) {
            int col = n0 + wn + n * 16 + (lane & 15);
#pragma unroll
            for (int j = 0; j < 4; ++j) {
                int row = row_base + j;
                float x = acc[m][n][j];
                if (MODE == 1) {
                    x += bias[col];
                    x = (x - mean[col]) * rsqrtf(var[col] + 1e-5f) * gamma[col] + beta[col];
                    x = (x >= 0.0f) ? x : alpha * x;
                } else {
                    x *= dinv[row];
                }
                Cout[(size_t)row * DD + col] = (__bf16)x;
            }
        }
    }
}

// ---------------- fused gather + dinv + bias + PReLU + L2 norm + residual ----------------
// 128 threads per node, 4 cols/thread. XCD-chunked node assignment for L2 locality.
__global__ __launch_bounds__(128) void k_gather_final(
    const int* __restrict__ offs, const int* __restrict__ csr,
    const __bf16* __restrict__ xws, const float* __restrict__ dinv,
    const float* __restrict__ bg, const float* __restrict__ alpha2,
    const float* __restrict__ text, float* __restrict__ out)
{
    int blk = blockIdx.x;
    int node = ((blk & 7) << 12) + (blk >> 3);   // 8 XCD chunks of 4096 consecutive nodes
    int t = threadIdx.x;
    int c = t * 4;
    int beg = offs[node], end = offs[node + 1];

    // self loop
    bf16x4 sv = *(const bf16x4*)(xws + (size_t)node * DD + c);
    float a0 = (float)sv[0], a1 = (float)sv[1], a2v = (float)sv[2], a3 = (float)sv[3];
    for (int e = beg; e < end; ++e) {
        int s = csr[e];
        bf16x4 v = *(const bf16x4*)(xws + (size_t)s * DD + c);
        a0 += (float)v[0]; a1 += (float)v[1]; a2v += (float)v[2]; a3 += (float)v[3];
    }

    float di = dinv[node];
    float al = alpha2[0];
    float4 bgv = *(const float4*)(bg + c);
    float g0 = a0 * di + bgv.x;
    float g1 = a1 * di + bgv.y;
    float g2 = a2v * di + bgv.z;
    float g3 = a3 * di + bgv.w;
    g0 = (g0 >= 0.0f) ? g0 : al * g0;
    g1 = (g1 >= 0.0f) ? g1 : al * g1;
    g2 = (g2 >= 0.0f) ? g2 : al * g2;
    g3 = (g3 >= 0.0f) ? g3 : al * g3;

    float ss = g0 * g0 + g1 * g1 + g2 * g2 + g3 * g3;
#pragma unroll
    for (int off = 32; off > 0; off >>= 1) ss += __shfl_down(ss, off, 64);
    __shared__ float red[2];
    if ((t & 63) == 0) red[t >> 6] = ss;
    __syncthreads();
    float inv = 1.0f / fmaxf(sqrtf(red[0] + red[1]), 1e-12f);

    float4 tx = *(const float4*)(text + (size_t)node * DD + c);
    float4 o;
    o.x = g0 * inv + tx.x;
    o.y = g1 * inv + tx.y;
    o.z = g2 * inv + tx.z;
    o.w = g3 * inv + tx.w;
    *(float4*)(out + (size_t)node * DD + c) = o;
}

extern "C" void kernel_launch(void* const* d_in, const int* in_sizes, int n_in,
                              void* d_out, int out_size, void* d_ws, size_t ws_size,
                              hipStream_t stream) {
    const float* text   = (const float*)d_in[0];
    const int*   esrc   = (const int*)d_in[1];
    const int*   edst   = (const int*)d_in[2];
    const float* W1     = (const float*)d_in[3];
    const float* b1     = (const float*)d_in[4];
    const float* gamma  = (const float*)d_in[5];
    const float* beta   = (const float*)d_in[6];
    const float* rmean  = (const float*)d_in[7];
    const float* rvar   = (const float*)d_in[8];
    const float* alpha1 = (const float*)d_in[9];
    const float* Wg     = (const float*)d_in[10];
    const float* bg     = (const float*)d_in[11];
    const float* alpha2 = (const float*)d_in[12];
    float* out = (float*)d_out;

    // workspace layout (~98.5 MiB)
    char* p = (char*)d_ws;
    auto alloc = [&](size_t bytes) { char* r = p; p += (bytes + 255) & ~(size_t)255; return r; };
    int*    cnt     = (int*)alloc((size_t)NN * 4);
    int*    offs    = (int*)alloc((size_t)(NN + 1) * 4);
    int*    cursor  = (int*)alloc((size_t)NN * 4);
    float*  dinv    = (float*)alloc((size_t)NN * 4);
    int*    csr     = (int*)alloc((size_t)EE * 4);
    __bf16* W1t     = (__bf16*)alloc((size_t)DD * DD * 2);
    __bf16* Wgt     = (__bf16*)alloc((size_t)DD * DD * 2);
    __bf16* h_bf    = (__bf16*)alloc((size_t)NN * DD * 2);
    __bf16* text_bf = (__bf16*)alloc((size_t)NN * DD * 2);
    __bf16* xws     = (__bf16*)alloc((size_t)NN * DD * 2);

    // 1) CSR build + dinv
    k_zero<<<NN / 256, 256, 0, stream>>>(cnt);
    k_count<<<EE / 256, 256, 0, stream>>>(edst, cnt);
    k_scan<<<1, 1024, 0, stream>>>(cnt, offs, cursor, dinv);
    k_fill<<<EE / 256, 256, 0, stream>>>(esrc, edst, cursor, csr);

    // 2) convert inputs to bf16
    k_cvt<<<(NN * DD / 4) / 256, 256, 0, stream>>>(text, text_bf);
    k_wt<<<dim3(16, 16, 2), dim3(32, 8), 0, stream>>>(W1, Wg, W1t, Wgt);

    // 3) h = PReLU(BN(text@W1 + b1))   [bf16 out]
    dim3 gg(NN / 128, DD / 128);
    k_gemm_mfma<1><<<gg, 256, 0, stream>>>(text_bf, W1t, h_bf, b1, gamma, beta, rmean, rvar, alpha1, nullptr);

    // 4) xws = (h@Wg) * dinv[row]     [bf16 out]
    k_gemm_mfma<2><<<gg, 256, 0, stream>>>(h_bf, Wgt, xws, nullptr, nullptr, nullptr, nullptr, nullptr, nullptr, dinv);

    // 5) fused gather + epilogue + L2 norm + residual
    k_gather_final<<<NN, 128, 0, stream>>>(offs, csr, xws, dinv, bg, alpha2, text, out);
}

// Round 5
// 165.943 us; speedup vs baseline: 13.8713x; 1.0439x over previous
//
#include <hip/hip_runtime.h>
#include <math.h>

#define DD    512
#define NN    32768      // B*L nodes
#define EE    262144     // edges (without self loops)

typedef float f32x4 __attribute__((ext_vector_type(4)));
typedef __bf16 bf16x8 __attribute__((ext_vector_type(8)));
typedef __bf16 bf16x4 __attribute__((ext_vector_type(4)));

// ---------------- CSR build ----------------
__global__ void k_zero(int* __restrict__ cnt) {
    int i = blockIdx.x * 256 + threadIdx.x;
    if (i < NN) cnt[i] = 0;
}

__global__ void k_count(const int* __restrict__ dst, int* __restrict__ cnt) {
    int e = blockIdx.x * 256 + threadIdx.x;
    if (e < EE) atomicAdd(&cnt[dst[e]], 1);
}

__global__ __launch_bounds__(1024) void k_scan(
    const int* __restrict__ cnt, int* __restrict__ offs,
    int* __restrict__ cursor, float* __restrict__ dinv)
{
    __shared__ int part[1024];
    int t = threadIdx.x;
    int base = t * 32;
    int local[32];
    int s = 0;
#pragma unroll
    for (int i = 0; i < 32; ++i) { local[i] = s; s += cnt[base + i]; }
    part[t] = s;
    __syncthreads();
    for (int off = 1; off < 1024; off <<= 1) {
        int v = (t >= off) ? part[t - off] : 0;
        __syncthreads();
        part[t] += v;
        __syncthreads();
    }
    int prev = (t == 0) ? 0 : part[t - 1];
#pragma unroll
    for (int i = 0; i < 32; ++i) {
        int o = prev + local[i];
        offs[base + i] = o;
        cursor[base + i] = o;
        dinv[base + i] = rsqrtf((float)cnt[base + i] + 1.0f);
    }
    if (t == 1023) offs[NN] = part[1023];
}

__global__ void k_fill(const int* __restrict__ src, const int* __restrict__ dst,
                       int* __restrict__ cursor, int* __restrict__ csr) {
    int e = blockIdx.x * 256 + threadIdx.x;
    if (e < EE) {
        int d = dst[e];
        int p = atomicAdd(&cursor[d], 1);
        csr[p] = src[e];
    }
}

// ---------------- weight transpose + convert: Wt[n][k] = (bf16)W[k][n] ----------------
__global__ __launch_bounds__(256) void k_wt(const float* __restrict__ W1, const float* __restrict__ Wg,
                                            __bf16* __restrict__ W1t, __bf16* __restrict__ Wgt) {
    __shared__ float tile[32][33];
    const float* W = blockIdx.z ? Wg : W1;
    __bf16* Wt = blockIdx.z ? Wgt : W1t;
    int x0 = blockIdx.x * 32;   // n block
    int y0 = blockIdx.y * 32;   // k block
    int tx = threadIdx.x;       // 0..31
    for (int j = threadIdx.y; j < 32; j += 8)
        tile[j][tx] = W[(size_t)(y0 + j) * DD + x0 + tx];
    __syncthreads();
    for (int j = threadIdx.y; j < 32; j += 8)
        Wt[(size_t)(x0 + j) * DD + y0 + tx] = (__bf16)tile[tx][j];
}

// ---------------- bf16 MFMA GEMM, 128x128 tile, BK=32, fused epilogues ----------------
// MODE 1: A is fp32 (text), reg-staged with inline cvt; out = PReLU(BN(A@B + b1)) bf16
// MODE 2: A is bf16 (h),   global_load_lds;             out = (A@B)*dinv[row]     bf16
// grid: (DD/128 n-tiles  [fast], NN/128 m-tiles) so same-A blocks dispatch adjacently
template <int MODE>
__global__ __launch_bounds__(256) void k_gemm_mfma(
    const void* __restrict__ Ap,
    const __bf16* __restrict__ Bt,
    __bf16* __restrict__ Cout,
    const float* __restrict__ bias,
    const float* __restrict__ gamma, const float* __restrict__ beta,
    const float* __restrict__ mean, const float* __restrict__ var,
    const float* __restrict__ alphap,
    const float* __restrict__ dinv)
{
    __shared__ __bf16 lds[2][128 * 32];

    const int tid  = threadIdx.x;
    const int lane = tid & 63;
    const int w    = tid >> 6;
    const int wm   = (w >> 1) * 64;
    const int wn   = (w & 1) * 64;
    const int n0   = blockIdx.x * 128;
    const int m0   = blockIdx.y * 128;

    f32x4 acc[4][4] = {};

    for (int k0 = 0; k0 < DD; k0 += 32) {
        __syncthreads();
        // B tile first (async loads fly under A staging work)
#pragma unroll
        for (int rd = 0; rd < 2; ++rd) {
            int cbase = rd * 256 + w * 64;
            int cidx = cbase + lane;
            int r = cidx >> 2, s = cidx & 3;
            int c = s ^ ((r >> 1) & 3);
            const __bf16* gb = Bt + (size_t)(n0 + r) * DD + k0 + c * 8;
            __builtin_amdgcn_global_load_lds(
                (const __attribute__((address_space(1))) unsigned int*)gb,
                (__attribute__((address_space(3))) unsigned int*)(&lds[1][cbase * 8]), 16, 0, 0);
        }
        if constexpr (MODE == 1) {
            // A fp32 reg-staged + inline cvt, same pre-swizzled linear layout
            const float* A = (const float*)Ap;
#pragma unroll
            for (int hh = 0; hh < 2; ++hh) {
                int ci = tid + hh * 256;
                int r = ci >> 2, s = ci & 3;
                int c = s ^ ((r >> 1) & 3);
                const float* ga = A + (size_t)(m0 + r) * DD + k0 + c * 8;
                float4 f0 = *(const float4*)ga;
                float4 f1 = *(const float4*)(ga + 4);
                bf16x8 o;
                o[0] = (__bf16)f0.x; o[1] = (__bf16)f0.y; o[2] = (__bf16)f0.z; o[3] = (__bf16)f0.w;
                o[4] = (__bf16)f1.x; o[5] = (__bf16)f1.y; o[6] = (__bf16)f1.z; o[7] = (__bf16)f1.w;
                *(bf16x8*)&lds[0][ci * 8] = o;
            }
        } else {
            const __bf16* A = (const __bf16*)Ap;
#pragma unroll
            for (int rd = 0; rd < 2; ++rd) {
                int cbase = rd * 256 + w * 64;
                int cidx = cbase + lane;
                int r = cidx >> 2, s = cidx & 3;
                int c = s ^ ((r >> 1) & 3);
                const __bf16* ga = A + (size_t)(m0 + r) * DD + k0 + c * 8;
                __builtin_amdgcn_global_load_lds(
                    (const __attribute__((address_space(1))) unsigned int*)ga,
                    (__attribute__((address_space(3))) unsigned int*)(&lds[0][cbase * 8]), 16, 0, 0);
            }
        }
        __syncthreads();

        bf16x8 af[4], bf[4];
#pragma unroll
        for (int m = 0; m < 4; ++m) {
            int r = wm + m * 16 + (lane & 15);
            int s = (lane >> 4) ^ ((r >> 1) & 3);
            af[m] = *(const bf16x8*)&lds[0][r * 32 + s * 8];
            int q = wn + m * 16 + (lane & 15);
            int sq = (lane >> 4) ^ ((q >> 1) & 3);
            bf[m] = *(const bf16x8*)&lds[1][q * 32 + sq * 8];
        }
#pragma unroll
        for (int m = 0; m < 4; ++m)
#pragma unroll
            for (int n = 0; n < 4; ++n)
                acc[m][n] = __builtin_amdgcn_mfma_f32_16x16x32_bf16(af[m], bf[n], acc[m][n], 0, 0, 0);
    }

    float alpha = (MODE == 1) ? alphap[0] : 0.0f;
#pragma unroll
    for (int m = 0; m < 4; ++m) {
        int row_base = m0 + wm + m * 16 + ((lane >> 4) << 2);
#pragma unroll
        for (int n = 0; n < 4; ++n) {
            int col = n0 + wn + n * 16 + (lane & 15);
#pragma unroll
            for (int j = 0; j < 4; ++j) {
                int row = row_base + j;
                float x = acc[m][n][j];
                if (MODE == 1) {
                    x += bias[col];
                    x = (x - mean[col]) * rsqrtf(var[col] + 1e-5f) * gamma[col] + beta[col];
                    x = (x >= 0.0f) ? x : alpha * x;
                } else {
                    x *= dinv[row];
                }
                Cout[(size_t)row * DD + col] = (__bf16)x;
            }
        }
    }
}

// ---------------- fused gather + dinv + bias + PReLU + L2 norm + residual ----------------
// One wave per node (4 nodes / 256-thread block), bf16x8 gathers, 4x-unrolled edge loop.
__global__ __launch_bounds__(256) void k_gather_final(
    const int* __restrict__ offs, const int* __restrict__ csr,
    const __bf16* __restrict__ xws, const float* __restrict__ dinv,
    const float* __restrict__ bg, const float* __restrict__ alpha2,
    const float* __restrict__ text, float* __restrict__ out)
{
    int blk = blockIdx.x;                              // 0..8191
    int sb  = ((blk & 7) << 10) + (blk >> 3);          // XCD-chunked (bijective: 8192 = 8*1024)
    int wave = threadIdx.x >> 6;
    int lane = threadIdx.x & 63;
    int node = sb * 4 + wave;
    int c = lane * 8;
    int beg = offs[node], end = offs[node + 1];
    int ne = end - beg;

    bf16x8 sv = *(const bf16x8*)(xws + (size_t)node * DD + c);   // self loop
    float a[8];
#pragma unroll
    for (int i = 0; i < 8; ++i) a[i] = (float)sv[i];

    int k = 0;
    for (; k + 4 <= ne; k += 4) {
        int s0 = csr[beg + k + 0];
        int s1 = csr[beg + k + 1];
        int s2 = csr[beg + k + 2];
        int s3 = csr[beg + k + 3];
        bf16x8 v0 = *(const bf16x8*)(xws + (size_t)s0 * DD + c);
        bf16x8 v1 = *(const bf16x8*)(xws + (size_t)s1 * DD + c);
        bf16x8 v2 = *(const bf16x8*)(xws + (size_t)s2 * DD + c);
        bf16x8 v3 = *(const bf16x8*)(xws + (size_t)s3 * DD + c);
#pragma unroll
        for (int i = 0; i < 8; ++i)
            a[i] += (float)v0[i] + (float)v1[i] + (float)v2[i] + (float)v3[i];
    }
    for (; k < ne; ++k) {
        int s = csr[beg + k];
        bf16x8 v = *(const bf16x8*)(xws + (size_t)s * DD + c);
#pragma unroll
        for (int i = 0; i < 8; ++i) a[i] += (float)v[i];
    }

    float di = dinv[node];
    float al = alpha2[0];
    float g[8];
    float ss = 0.0f;
#pragma unroll
    for (int i = 0; i < 8; ++i) {
        float x = a[i] * di + bg[c + i];
        x = (x >= 0.0f) ? x : al * x;
        g[i] = x;
        ss += x * x;
    }
#pragma unroll
    for (int off = 1; off < 64; off <<= 1) ss += __shfl_xor(ss, off, 64);
    float inv = 1.0f / fmaxf(sqrtf(ss), 1e-12f);

    float4 t0 = *(const float4*)(text + (size_t)node * DD + c);
    float4 t1 = *(const float4*)(text + (size_t)node * DD + c + 4);
    float4 o0, o1;
    o0.x = g[0] * inv + t0.x; o0.y = g[1] * inv + t0.y;
    o0.z = g[2] * inv + t0.z; o0.w = g[3] * inv + t0.w;
    o1.x = g[4] * inv + t1.x; o1.y = g[5] * inv + t1.y;
    o1.z = g[6] * inv + t1.z; o1.w = g[7] * inv + t1.w;
    *(float4*)(out + (size_t)node * DD + c)     = o0;
    *(float4*)(out + (size_t)node * DD + c + 4) = o1;
}

extern "C" void kernel_launch(void* const* d_in, const int* in_sizes, int n_in,
                              void* d_out, int out_size, void* d_ws, size_t ws_size,
                              hipStream_t stream) {
    const float* text   = (const float*)d_in[0];
    const int*   esrc   = (const int*)d_in[1];
    const int*   edst   = (const int*)d_in[2];
    const float* W1     = (const float*)d_in[3];
    const float* b1     = (const float*)d_in[4];
    const float* gamma  = (const float*)d_in[5];
    const float* beta   = (const float*)d_in[6];
    const float* rmean  = (const float*)d_in[7];
    const float* rvar   = (const float*)d_in[8];
    const float* alpha1 = (const float*)d_in[9];
    const float* Wg     = (const float*)d_in[10];
    const float* bg     = (const float*)d_in[11];
    const float* alpha2 = (const float*)d_in[12];
    float* out = (float*)d_out;

    // workspace layout (~66.5 MiB)
    char* p = (char*)d_ws;
    auto alloc = [&](size_t bytes) { char* r = p; p += (bytes + 255) & ~(size_t)255; return r; };
    int*    cnt     = (int*)alloc((size_t)NN * 4);
    int*    offs    = (int*)alloc((size_t)(NN + 1) * 4);
    int*    cursor  = (int*)alloc((size_t)NN * 4);
    float*  dinv    = (float*)alloc((size_t)NN * 4);
    int*    csr     = (int*)alloc((size_t)EE * 4);
    __bf16* W1t     = (__bf16*)alloc((size_t)DD * DD * 2);
    __bf16* Wgt     = (__bf16*)alloc((size_t)DD * DD * 2);
    __bf16* h_bf    = (__bf16*)alloc((size_t)NN * DD * 2);
    __bf16* xws     = (__bf16*)alloc((size_t)NN * DD * 2);

    // 1) CSR build + dinv
    k_zero<<<NN / 256, 256, 0, stream>>>(cnt);
    k_count<<<EE / 256, 256, 0, stream>>>(edst, cnt);
    k_scan<<<1, 1024, 0, stream>>>(cnt, offs, cursor, dinv);
    k_fill<<<EE / 256, 256, 0, stream>>>(esrc, edst, cursor, csr);

    // 2) weights -> bf16 [n][k]
    k_wt<<<dim3(16, 16, 2), dim3(32, 8), 0, stream>>>(W1, Wg, W1t, Wgt);

    // 3) h = PReLU(BN(text@W1 + b1))   [fp32 A inline-cvt, bf16 out]
    dim3 gg(DD / 128, NN / 128);    // n fast
    k_gemm_mfma<1><<<gg, 256, 0, stream>>>(text, W1t, h_bf, b1, gamma, beta, rmean, rvar, alpha1, nullptr);

    // 4) xws = (h@Wg) * dinv[row]     [bf16 out]
    k_gemm_mfma<2><<<gg, 256, 0, stream>>>(h_bf, Wgt, xws, nullptr, nullptr, nullptr, nullptr, nullptr, nullptr, dinv);

    // 5) fused gather + epilogue + L2 norm + residual
    k_gather_final<<<NN / 4, 256, 0, stream>>>(offs, csr, xws, dinv, bg, alpha2, text, out);
}

// Round 6
// 154.398 us; speedup vs baseline: 14.9085x; 1.0748x over previous
//
#include <hip/hip_runtime.h>
#include <math.h>

#define DD    512
#define NN    32768      // B*L nodes
#define EE    262144     // edges (without self loops)

typedef float f32x4 __attribute__((ext_vector_type(4)));
typedef __bf16 bf16x8 __attribute__((ext_vector_type(8)));
typedef __bf16 bf16x4 __attribute__((ext_vector_type(4)));

// ---------------- CSR build ----------------
__global__ void k_zero(int* __restrict__ cnt) {
    int i = blockIdx.x * 256 + threadIdx.x;
    if (i < NN) cnt[i] = 0;
}

__global__ void k_count(const int* __restrict__ dst, int* __restrict__ cnt) {
    int e = blockIdx.x * 256 + threadIdx.x;
    if (e < EE) atomicAdd(&cnt[dst[e]], 1);
}

__global__ __launch_bounds__(1024) void k_scan(
    const int* __restrict__ cnt, int* __restrict__ offs,
    int* __restrict__ cursor, float* __restrict__ dinv)
{
    __shared__ int part[1024];
    int t = threadIdx.x;
    int base = t * 32;
    int local[32];
    int s = 0;
#pragma unroll
    for (int i = 0; i < 32; ++i) { local[i] = s; s += cnt[base + i]; }
    part[t] = s;
    __syncthreads();
    for (int off = 1; off < 1024; off <<= 1) {
        int v = (t >= off) ? part[t - off] : 0;
        __syncthreads();
        part[t] += v;
        __syncthreads();
    }
    int prev = (t == 0) ? 0 : part[t - 1];
#pragma unroll
    for (int i = 0; i < 32; ++i) {
        int o = prev + local[i];
        offs[base + i] = o;
        cursor[base + i] = o;
        dinv[base + i] = rsqrtf((float)cnt[base + i] + 1.0f);
    }
    if (t == 1023) offs[NN] = part[1023];
}

__global__ void k_fill(const int* __restrict__ src, const int* __restrict__ dst,
                       int* __restrict__ cursor, int* __restrict__ csr) {
    int e = blockIdx.x * 256 + threadIdx.x;
    if (e < EE) {
        int d = dst[e];
        int p = atomicAdd(&cursor[d], 1);
        csr[p] = src[e];
    }
}

// ---------------- weight transpose + convert: Wt[n][k] = (bf16)W[k][n] ----------------
__global__ __launch_bounds__(256) void k_wt(const float* __restrict__ W1, const float* __restrict__ Wg,
                                            __bf16* __restrict__ W1t, __bf16* __restrict__ Wgt) {
    __shared__ float tile[32][33];
    const float* W = blockIdx.z ? Wg : W1;
    __bf16* Wt = blockIdx.z ? Wgt : W1t;
    int x0 = blockIdx.x * 32;   // n block
    int y0 = blockIdx.y * 32;   // k block
    int tx = threadIdx.x;       // 0..31
    for (int j = threadIdx.y; j < 32; j += 8)
        tile[j][tx] = W[(size_t)(y0 + j) * DD + x0 + tx];
    __syncthreads();
    for (int j = threadIdx.y; j < 32; j += 8)
        Wt[(size_t)(x0 + j) * DD + y0 + tx] = (__bf16)tile[tx][j];
}

// ---------------- bf16 MFMA GEMM, 128x128 tile, BK=32, fused epilogues ----------------
// MODE 1: A is fp32 (text), reg-staged with inline cvt; out = PReLU(BN(A@B + b1)) bf16
// MODE 2: A is bf16 (h),   global_load_lds;             out = (A@B)*dinv[row]     bf16
// Grid: 1D 1024 blocks, XCD-affinity swizzle: XCD j owns m-panels [32j,32j+32),
// and the 4 n-tiles of one m-panel launch consecutively on the SAME XCD so the
// A-panel (256KB fp32 / 128KB bf16) is L2-resident across its 4 reuses.
template <int MODE>
__global__ __launch_bounds__(256) void k_gemm_mfma(
    const void* __restrict__ Ap,
    const __bf16* __restrict__ Bt,
    __bf16* __restrict__ Cout,
    const float* __restrict__ bias,
    const float* __restrict__ gamma, const float* __restrict__ beta,
    const float* __restrict__ mean, const float* __restrict__ var,
    const float* __restrict__ alphap,
    const float* __restrict__ dinv)
{
    __shared__ __bf16 lds[2][128 * 32];

    const int tid  = threadIdx.x;
    const int lane = tid & 63;
    const int w    = tid >> 6;
    const int wm   = (w >> 1) * 64;
    const int wn   = (w & 1) * 64;
    const int work = ((blockIdx.x & 7) << 7) + (blockIdx.x >> 3);  // bijective, 1024
    const int m0   = (work >> 2) * 128;
    const int n0   = (work & 3) * 128;

    f32x4 acc[4][4] = {};

    for (int k0 = 0; k0 < DD; k0 += 32) {
        __syncthreads();
        // B tile (async loads fly under A staging work)
#pragma unroll
        for (int rd = 0; rd < 2; ++rd) {
            int cbase = rd * 256 + w * 64;
            int cidx = cbase + lane;
            int r = cidx >> 2, s = cidx & 3;
            int c = s ^ ((r >> 1) & 3);
            const __bf16* gb = Bt + (size_t)(n0 + r) * DD + k0 + c * 8;
            __builtin_amdgcn_global_load_lds(
                (const __attribute__((address_space(1))) unsigned int*)gb,
                (__attribute__((address_space(3))) unsigned int*)(&lds[1][cbase * 8]), 16, 0, 0);
        }
        if constexpr (MODE == 1) {
            const float* A = (const float*)Ap;
#pragma unroll
            for (int hh = 0; hh < 2; ++hh) {
                int ci = tid + hh * 256;
                int r = ci >> 2, s = ci & 3;
                int c = s ^ ((r >> 1) & 3);
                const float* ga = A + (size_t)(m0 + r) * DD + k0 + c * 8;
                float4 f0 = *(const float4*)ga;
                float4 f1 = *(const float4*)(ga + 4);
                bf16x8 o;
                o[0] = (__bf16)f0.x; o[1] = (__bf16)f0.y; o[2] = (__bf16)f0.z; o[3] = (__bf16)f0.w;
                o[4] = (__bf16)f1.x; o[5] = (__bf16)f1.y; o[6] = (__bf16)f1.z; o[7] = (__bf16)f1.w;
                *(bf16x8*)&lds[0][ci * 8] = o;
            }
        } else {
            const __bf16* A = (const __bf16*)Ap;
#pragma unroll
            for (int rd = 0; rd < 2; ++rd) {
                int cbase = rd * 256 + w * 64;
                int cidx = cbase + lane;
                int r = cidx >> 2, s = cidx & 3;
                int c = s ^ ((r >> 1) & 3);
                const __bf16* ga = A + (size_t)(m0 + r) * DD + k0 + c * 8;
                __builtin_amdgcn_global_load_lds(
                    (const __attribute__((address_space(1))) unsigned int*)ga,
                    (__attribute__((address_space(3))) unsigned int*)(&lds[0][cbase * 8]), 16, 0, 0);
            }
        }
        __syncthreads();

        bf16x8 af[4], bf[4];
#pragma unroll
        for (int m = 0; m < 4; ++m) {
            int r = wm + m * 16 + (lane & 15);
            int s = (lane >> 4) ^ ((r >> 1) & 3);
            af[m] = *(const bf16x8*)&lds[0][r * 32 + s * 8];
            int q = wn + m * 16 + (lane & 15);
            int sq = (lane >> 4) ^ ((q >> 1) & 3);
            bf[m] = *(const bf16x8*)&lds[1][q * 32 + sq * 8];
        }
#pragma unroll
        for (int m = 0; m < 4; ++m)
#pragma unroll
            for (int n = 0; n < 4; ++n)
                acc[m][n] = __builtin_amdgcn_mfma_f32_16x16x32_bf16(af[m], bf[n], acc[m][n], 0, 0, 0);
    }

    float alpha = (MODE == 1) ? alphap[0] : 0.0f;
#pragma unroll
    for (int m = 0; m < 4; ++m) {
        int row_base = m0 + wm + m * 16 + ((lane >> 4) << 2);
#pragma unroll
        for (int n = 0; n < 4; ++n) {
            int col = n0 + wn + n * 16 + (lane & 15);
#pragma unroll
            for (int j = 0; j < 4; ++j) {
                int row = row_base + j;
                float x = acc[m][n][j];
                if (MODE == 1) {
                    x += bias[col];
                    x = (x - mean[col]) * rsqrtf(var[col] + 1e-5f) * gamma[col] + beta[col];
                    x = (x >= 0.0f) ? x : alpha * x;
                } else {
                    x *= dinv[row];
                }
                Cout[(size_t)row * DD + col] = (__bf16)x;
            }
        }
    }
}

// ---------------- fused gather + dinv + bias + PReLU + L2 norm + residual ----------------
// One wave per node (4 nodes / 256-thread block), bf16x8 gathers, 4x-unrolled edge loop.
__global__ __launch_bounds__(256) void k_gather_final(
    const int* __restrict__ offs, const int* __restrict__ csr,
    const __bf16* __restrict__ xws, const float* __restrict__ dinv,
    const float* __restrict__ bg, const float* __restrict__ alpha2,
    const float* __restrict__ text, float* __restrict__ out)
{
    int blk = blockIdx.x;                              // 0..8191
    int sb  = ((blk & 7) << 10) + (blk >> 3);          // XCD-chunked (bijective: 8192 = 8*1024)
    int wave = threadIdx.x >> 6;
    int lane = threadIdx.x & 63;
    int node = sb * 4 + wave;
    int c = lane * 8;
    int beg = offs[node], end = offs[node + 1];
    int ne = end - beg;

    bf16x8 sv = *(const bf16x8*)(xws + (size_t)node * DD + c);   // self loop
    float a[8];
#pragma unroll
    for (int i = 0; i < 8; ++i) a[i] = (float)sv[i];

    int k = 0;
    for (; k + 4 <= ne; k += 4) {
        int s0 = csr[beg + k + 0];
        int s1 = csr[beg + k + 1];
        int s2 = csr[beg + k + 2];
        int s3 = csr[beg + k + 3];
        bf16x8 v0 = *(const bf16x8*)(xws + (size_t)s0 * DD + c);
        bf16x8 v1 = *(const bf16x8*)(xws + (size_t)s1 * DD + c);
        bf16x8 v2 = *(const bf16x8*)(xws + (size_t)s2 * DD + c);
        bf16x8 v3 = *(const bf16x8*)(xws + (size_t)s3 * DD + c);
#pragma unroll
        for (int i = 0; i < 8; ++i)
            a[i] += (float)v0[i] + (float)v1[i] + (float)v2[i] + (float)v3[i];
    }
    for (; k < ne; ++k) {
        int s = csr[beg + k];
        bf16x8 v = *(const bf16x8*)(xws + (size_t)s * DD + c);
#pragma unroll
        for (int i = 0; i < 8; ++i) a[i] += (float)v[i];
    }

    float di = dinv[node];
    float al = alpha2[0];
    float g[8];
    float ss = 0.0f;
#pragma unroll
    for (int i = 0; i < 8; ++i) {
        float x = a[i] * di + bg[c + i];
        x = (x >= 0.0f) ? x : al * x;
        g[i] = x;
        ss += x * x;
    }
#pragma unroll
    for (int off = 1; off < 64; off <<= 1) ss += __shfl_xor(ss, off, 64);
    float inv = 1.0f / fmaxf(sqrtf(ss), 1e-12f);

    float4 t0 = *(const float4*)(text + (size_t)node * DD + c);
    float4 t1 = *(const float4*)(text + (size_t)node * DD + c + 4);
    float4 o0, o1;
    o0.x = g[0] * inv + t0.x; o0.y = g[1] * inv + t0.y;
    o0.z = g[2] * inv + t0.z; o0.w = g[3] * inv + t0.w;
    o1.x = g[4] * inv + t1.x; o1.y = g[5] * inv + t1.y;
    o1.z = g[6] * inv + t1.z; o1.w = g[7] * inv + t1.w;
    *(float4*)(out + (size_t)node * DD + c)     = o0;
    *(float4*)(out + (size_t)node * DD + c + 4) = o1;
}

extern "C" void kernel_launch(void* const* d_in, const int* in_sizes, int n_in,
                              void* d_out, int out_size, void* d_ws, size_t ws_size,
                              hipStream_t stream) {
    const float* text   = (const float*)d_in[0];
    const int*   esrc   = (const int*)d_in[1];
    const int*   edst   = (const int*)d_in[2];
    const float* W1     = (const float*)d_in[3];
    const float* b1     = (const float*)d_in[4];
    const float* gamma  = (const float*)d_in[5];
    const float* beta   = (const float*)d_in[6];
    const float* rmean  = (const float*)d_in[7];
    const float* rvar   = (const float*)d_in[8];
    const float* alpha1 = (const float*)d_in[9];
    const float* Wg     = (const float*)d_in[10];
    const float* bg     = (const float*)d_in[11];
    const float* alpha2 = (const float*)d_in[12];
    float* out = (float*)d_out;

    // workspace layout (~66.5 MiB)
    char* p = (char*)d_ws;
    auto alloc = [&](size_t bytes) { char* r = p; p += (bytes + 255) & ~(size_t)255; return r; };
    int*    cnt     = (int*)alloc((size_t)NN * 4);
    int*    offs    = (int*)alloc((size_t)(NN + 1) * 4);
    int*    cursor  = (int*)alloc((size_t)NN * 4);
    float*  dinv    = (float*)alloc((size_t)NN * 4);
    int*    csr     = (int*)alloc((size_t)EE * 4);
    __bf16* W1t     = (__bf16*)alloc((size_t)DD * DD * 2);
    __bf16* Wgt     = (__bf16*)alloc((size_t)DD * DD * 2);
    __bf16* h_bf    = (__bf16*)alloc((size_t)NN * DD * 2);
    __bf16* xws     = (__bf16*)alloc((size_t)NN * DD * 2);

    // 1) CSR build + dinv
    k_zero<<<NN / 256, 256, 0, stream>>>(cnt);
    k_count<<<EE / 256, 256, 0, stream>>>(edst, cnt);
    k_scan<<<1, 1024, 0, stream>>>(cnt, offs, cursor, dinv);
    k_fill<<<EE / 256, 256, 0, stream>>>(esrc, edst, cursor, csr);

    // 2) weights -> bf16 [n][k]
    k_wt<<<dim3(16, 16, 2), dim3(32, 8), 0, stream>>>(W1, Wg, W1t, Wgt);

    // 3) h = PReLU(BN(text@W1 + b1))   [fp32 A inline-cvt, bf16 out]
    k_gemm_mfma<1><<<1024, 256, 0, stream>>>(text, W1t, h_bf, b1, gamma, beta, rmean, rvar, alpha1, nullptr);

    // 4) xws = (h@Wg) * dinv[row]     [bf16 out]
    k_gemm_mfma<2><<<1024, 256, 0, stream>>>(h_bf, Wgt, xws, nullptr, nullptr, nullptr, nullptr, nullptr, nullptr, dinv);

    // 5) fused gather + epilogue + L2 norm + residual
    k_gather_final<<<NN / 4, 256, 0, stream>>>(offs, csr, xws, dinv, bg, alpha2, text, out);
}

// Round 7
// 152.172 us; speedup vs baseline: 15.1266x; 1.0146x over previous
//
#include <hip/hip_runtime.h>
#include <math.h>

#define DD    512
#define NN    32768      // B*L nodes
#define EE    262144     // edges (without self loops)

typedef float f32x4 __attribute__((ext_vector_type(4)));
typedef __bf16 bf16x8 __attribute__((ext_vector_type(8)));
typedef __bf16 bf16x4 __attribute__((ext_vector_type(4)));

// ---------------- CSR build ----------------
__global__ void k_zero(int* __restrict__ cnt) {
    int i = blockIdx.x * 256 + threadIdx.x;
    if (i < NN) cnt[i] = 0;
}

__global__ void k_count(const int* __restrict__ dst, int* __restrict__ cnt) {
    int e = blockIdx.x * 256 + threadIdx.x;
    if (e < EE) atomicAdd(&cnt[dst[e]], 1);
}

__global__ __launch_bounds__(1024) void k_scan(
    const int* __restrict__ cnt, int* __restrict__ offs,
    int* __restrict__ cursor, float* __restrict__ dinv)
{
    __shared__ int part[1024];
    int t = threadIdx.x;
    int base = t * 32;
    int local[32];
    int s = 0;
#pragma unroll
    for (int i = 0; i < 32; ++i) { local[i] = s; s += cnt[base + i]; }
    part[t] = s;
    __syncthreads();
    for (int off = 1; off < 1024; off <<= 1) {
        int v = (t >= off) ? part[t - off] : 0;
        __syncthreads();
        part[t] += v;
        __syncthreads();
    }
    int prev = (t == 0) ? 0 : part[t - 1];
#pragma unroll
    for (int i = 0; i < 32; ++i) {
        int o = prev + local[i];
        offs[base + i] = o;
        cursor[base + i] = o;
        dinv[base + i] = rsqrtf((float)cnt[base + i] + 1.0f);
    }
    if (t == 1023) offs[NN] = part[1023];
}

__global__ void k_fill(const int* __restrict__ src, const int* __restrict__ dst,
                       int* __restrict__ cursor, int* __restrict__ csr) {
    int e = blockIdx.x * 256 + threadIdx.x;
    if (e < EE) {
        int d = dst[e];
        int p = atomicAdd(&cursor[d], 1);
        csr[p] = src[e];
    }
}

// ---------------- weight transpose + convert: Wt[n][k] = (bf16)W[k][n] ----------------
__global__ __launch_bounds__(256) void k_wt(const float* __restrict__ W1, const float* __restrict__ Wg,
                                            __bf16* __restrict__ W1t, __bf16* __restrict__ Wgt) {
    __shared__ float tile[32][33];
    const float* W = blockIdx.z ? Wg : W1;
    __bf16* Wt = blockIdx.z ? Wgt : W1t;
    int x0 = blockIdx.x * 32;   // n block
    int y0 = blockIdx.y * 32;   // k block
    int tx = threadIdx.x;       // 0..31
    for (int j = threadIdx.y; j < 32; j += 8)
        tile[j][tx] = W[(size_t)(y0 + j) * DD + x0 + tx];
    __syncthreads();
    for (int j = threadIdx.y; j < 32; j += 8)
        Wt[(size_t)(x0 + j) * DD + y0 + tx] = (__bf16)tile[tx][j];
}

// ---------------- bf16 MFMA GEMM, 128x128 tile, BK=32, double-buffered pipeline ----------------
// MODE 1: A fp32 (text), reg-staged + inline cvt (T14 split); out = PReLU(BN(A@B+b1)) bf16
// MODE 2: A bf16 (h), global_load_lds;                        out = (A@B)*dinv[row]  bf16
// 2-phase pipeline: ds_read cur frags -> issue nxt stage -> MFMA -> (writeA) -> 1 barrier.
// Grid: 1D 1024, XCD-affinity swizzle (same-panel n-tiles on same XCD for L2 A-reuse).
template <int MODE>
__global__ __launch_bounds__(256) void k_gemm_mfma(
    const void* __restrict__ Ap,
    const __bf16* __restrict__ Bt,
    __bf16* __restrict__ Cout,
    const float* __restrict__ bias,
    const float* __restrict__ gamma, const float* __restrict__ beta,
    const float* __restrict__ mean, const float* __restrict__ var,
    const float* __restrict__ alphap,
    const float* __restrict__ dinv)
{
    __shared__ __bf16 As[2][128 * 32];
    __shared__ __bf16 Bs[2][128 * 32];

    const int tid  = threadIdx.x;
    const int lane = tid & 63;
    const int w    = tid >> 6;
    const int wm   = (w >> 1) * 64;
    const int wn   = (w & 1) * 64;
    const int work = ((blockIdx.x & 7) << 7) + (blockIdx.x >> 3);  // bijective, 1024
    const int m0   = (work >> 2) * 128;
    const int n0   = (work & 3) * 128;

    f32x4 acc[4][4] = {};
    float4 fa[2][2];   // MODE1 A-staging registers

    // --- staging helpers (same pre-swizzled linear layout as before) ---
    auto stageB = [&](int bb, int k0) {
#pragma unroll
        for (int rd = 0; rd < 2; ++rd) {
            int cbase = rd * 256 + w * 64;
            int cidx = cbase + lane;
            int r = cidx >> 2, s = cidx & 3;
            int c = s ^ ((r >> 1) & 3);
            const __bf16* gb = Bt + (size_t)(n0 + r) * DD + k0 + c * 8;
            __builtin_amdgcn_global_load_lds(
                (const __attribute__((address_space(1))) unsigned int*)gb,
                (__attribute__((address_space(3))) unsigned int*)(&Bs[bb][cbase * 8]), 16, 0, 0);
        }
    };
    auto stageA_lds = [&](int bb, int k0) {
        const __bf16* A = (const __bf16*)Ap;
#pragma unroll
        for (int rd = 0; rd < 2; ++rd) {
            int cbase = rd * 256 + w * 64;
            int cidx = cbase + lane;
            int r = cidx >> 2, s = cidx & 3;
            int c = s ^ ((r >> 1) & 3);
            const __bf16* ga = A + (size_t)(m0 + r) * DD + k0 + c * 8;
            __builtin_amdgcn_global_load_lds(
                (const __attribute__((address_space(1))) unsigned int*)ga,
                (__attribute__((address_space(3))) unsigned int*)(&As[bb][cbase * 8]), 16, 0, 0);
        }
    };
    auto loadA = [&](int k0) {
        const float* A = (const float*)Ap;
#pragma unroll
        for (int hh = 0; hh < 2; ++hh) {
            int ci = tid + hh * 256;
            int r = ci >> 2, s = ci & 3;
            int c = s ^ ((r >> 1) & 3);
            const float* ga = A + (size_t)(m0 + r) * DD + k0 + c * 8;
            fa[hh][0] = *(const float4*)ga;
            fa[hh][1] = *(const float4*)(ga + 4);
        }
    };
    auto writeA = [&](int bb) {
#pragma unroll
        for (int hh = 0; hh < 2; ++hh) {
            int ci = tid + hh * 256;
            bf16x8 o;
            o[0] = (__bf16)fa[hh][0].x; o[1] = (__bf16)fa[hh][0].y;
            o[2] = (__bf16)fa[hh][0].z; o[3] = (__bf16)fa[hh][0].w;
            o[4] = (__bf16)fa[hh][1].x; o[5] = (__bf16)fa[hh][1].y;
            o[6] = (__bf16)fa[hh][1].z; o[7] = (__bf16)fa[hh][1].w;
            *(bf16x8*)&As[bb][ci * 8] = o;
        }
    };

    // --- prologue: stage tile 0 into buffer 0 ---
    if constexpr (MODE == 1) {
        loadA(0);
        stageB(0, 0);
        writeA(0);           // compiler waits vmcnt on fa use
    } else {
        stageA_lds(0, 0);
        stageB(0, 0);
    }
    __syncthreads();

    // --- pipelined K loop: 16 steps, fully unrolled (compile-time buffers) ---
#pragma unroll
    for (int kt = 0; kt < 16; ++kt) {
        const int cur = kt & 1;
        const int nxt = cur ^ 1;
        const int k1  = (kt + 1) * 32;

        // 1) frags of current tile
        bf16x8 af[4], bfr[4];
#pragma unroll
        for (int m = 0; m < 4; ++m) {
            int r = wm + m * 16 + (lane & 15);
            int s = (lane >> 4) ^ ((r >> 1) & 3);
            af[m] = *(const bf16x8*)&As[cur][r * 32 + s * 8];
            int q = wn + m * 16 + (lane & 15);
            int sq = (lane >> 4) ^ ((q >> 1) & 3);
            bfr[m] = *(const bf16x8*)&Bs[cur][q * 32 + sq * 8];
        }

        // 2) issue next tile's loads (fly under the MFMAs)
        if (kt < 15) {
            if constexpr (MODE == 1) loadA(k1);
            else                     stageA_lds(nxt, k1);
            stageB(nxt, k1);
        }

        // 3) compute
#pragma unroll
        for (int m = 0; m < 4; ++m)
#pragma unroll
            for (int n = 0; n < 4; ++n)
                acc[m][n] = __builtin_amdgcn_mfma_f32_16x16x32_bf16(af[m], bfr[n], acc[m][n], 0, 0, 0);

        // 4) MODE1: convert+write A regs into next buffer (after compute)
        if constexpr (MODE == 1) {
            if (kt < 15) writeA(nxt);
        }

        // 5) one barrier per K-step (drains lds-direct loads + ds_writes)
        __syncthreads();
    }

    // --- epilogue: C/D layout col = lane&15, row = (lane>>4)*4 + j ---
    float alpha = (MODE == 1) ? alphap[0] : 0.0f;
#pragma unroll
    for (int m = 0; m < 4; ++m) {
        int row_base = m0 + wm + m * 16 + ((lane >> 4) << 2);
#pragma unroll
        for (int n = 0; n < 4; ++n) {
            int col = n0 + wn + n * 16 + (lane & 15);
#pragma unroll
            for (int j = 0; j < 4; ++j) {
                int row = row_base + j;
                float x = acc[m][n][j];
                if (MODE == 1) {
                    x += bias[col];
                    x = (x - mean[col]) * rsqrtf(var[col] + 1e-5f) * gamma[col] + beta[col];
                    x = (x >= 0.0f) ? x : alpha * x;
                } else {
                    x *= dinv[row];
                }
                Cout[(size_t)row * DD + col] = (__bf16)x;
            }
        }
    }
}

// ---------------- fused gather + dinv + bias + PReLU + L2 norm + residual ----------------
__global__ __launch_bounds__(256) void k_gather_final(
    const int* __restrict__ offs, const int* __restrict__ csr,
    const __bf16* __restrict__ xws, const float* __restrict__ dinv,
    const float* __restrict__ bg, const float* __restrict__ alpha2,
    const float* __restrict__ text, float* __restrict__ out)
{
    int blk = blockIdx.x;                              // 0..8191
    int sb  = ((blk & 7) << 10) + (blk >> 3);          // XCD-chunked (bijective)
    int wave = threadIdx.x >> 6;
    int lane = threadIdx.x & 63;
    int node = sb * 4 + wave;
    int c = lane * 8;
    int beg = offs[node], end = offs[node + 1];
    int ne = end - beg;

    bf16x8 sv = *(const bf16x8*)(xws + (size_t)node * DD + c);   // self loop
    float a[8];
#pragma unroll
    for (int i = 0; i < 8; ++i) a[i] = (float)sv[i];

    int k = 0;
    for (; k + 4 <= ne; k += 4) {
        int s0 = csr[beg + k + 0];
        int s1 = csr[beg + k + 1];
        int s2 = csr[beg + k + 2];
        int s3 = csr[beg + k + 3];
        bf16x8 v0 = *(const bf16x8*)(xws + (size_t)s0 * DD + c);
        bf16x8 v1 = *(const bf16x8*)(xws + (size_t)s1 * DD + c);
        bf16x8 v2 = *(const bf16x8*)(xws + (size_t)s2 * DD + c);
        bf16x8 v3 = *(const bf16x8*)(xws + (size_t)s3 * DD + c);
#pragma unroll
        for (int i = 0; i < 8; ++i)
            a[i] += (float)v0[i] + (float)v1[i] + (float)v2[i] + (float)v3[i];
    }
    for (; k < ne; ++k) {
        int s = csr[beg + k];
        bf16x8 v = *(const bf16x8*)(xws + (size_t)s * DD + c);
#pragma unroll
        for (int i = 0; i < 8; ++i) a[i] += (float)v[i];
    }

    float di = dinv[node];
    float al = alpha2[0];
    float g[8];
    float ss = 0.0f;
#pragma unroll
    for (int i = 0; i < 8; ++i) {
        float x = a[i] * di + bg[c + i];
        x = (x >= 0.0f) ? x : al * x;
        g[i] = x;
        ss += x * x;
    }
#pragma unroll
    for (int off = 1; off < 64; off <<= 1) ss += __shfl_xor(ss, off, 64);
    float inv = 1.0f / fmaxf(sqrtf(ss), 1e-12f);

    float4 t0 = *(const float4*)(text + (size_t)node * DD + c);
    float4 t1 = *(const float4*)(text + (size_t)node * DD + c + 4);
    float4 o0, o1;
    o0.x = g[0] * inv + t0.x; o0.y = g[1] * inv + t0.y;
    o0.z = g[2] * inv + t0.z; o0.w = g[3] * inv + t0.w;
    o1.x = g[4] * inv + t1.x; o1.y = g[5] * inv + t1.y;
    o1.z = g[6] * inv + t1.z; o1.w = g[7] * inv + t1.w;
    *(float4*)(out + (size_t)node * DD + c)     = o0;
    *(float4*)(out + (size_t)node * DD + c + 4) = o1;
}

extern "C" void kernel_launch(void* const* d_in, const int* in_sizes, int n_in,
                              void* d_out, int out_size, void* d_ws, size_t ws_size,
                              hipStream_t stream) {
    const float* text   = (const float*)d_in[0];
    const int*   esrc   = (const int*)d_in[1];
    const int*   edst   = (const int*)d_in[2];
    const float* W1     = (const float*)d_in[3];
    const float* b1     = (const float*)d_in[4];
    const float* gamma  = (const float*)d_in[5];
    const float* beta   = (const float*)d_in[6];
    const float* rmean  = (const float*)d_in[7];
    const float* rvar   = (const float*)d_in[8];
    const float* alpha1 = (const float*)d_in[9];
    const float* Wg     = (const float*)d_in[10];
    const float* bg     = (const float*)d_in[11];
    const float* alpha2 = (const float*)d_in[12];
    float* out = (float*)d_out;

    // workspace layout (~66.5 MiB)
    char* p = (char*)d_ws;
    auto alloc = [&](size_t bytes) { char* r = p; p += (bytes + 255) & ~(size_t)255; return r; };
    int*    cnt     = (int*)alloc((size_t)NN * 4);
    int*    offs    = (int*)alloc((size_t)(NN + 1) * 4);
    int*    cursor  = (int*)alloc((size_t)NN * 4);
    float*  dinv    = (float*)alloc((size_t)NN * 4);
    int*    csr     = (int*)alloc((size_t)EE * 4);
    __bf16* W1t     = (__bf16*)alloc((size_t)DD * DD * 2);
    __bf16* Wgt     = (__bf16*)alloc((size_t)DD * DD * 2);
    __bf16* h_bf    = (__bf16*)alloc((size_t)NN * DD * 2);
    __bf16* xws     = (__bf16*)alloc((size_t)NN * DD * 2);

    // 1) CSR build + dinv
    k_zero<<<NN / 256, 256, 0, stream>>>(cnt);
    k_count<<<EE / 256, 256, 0, stream>>>(edst, cnt);
    k_scan<<<1, 1024, 0, stream>>>(cnt, offs, cursor, dinv);
    k_fill<<<EE / 256, 256, 0, stream>>>(esrc, edst, cursor, csr);

    // 2) weights -> bf16 [n][k]
    k_wt<<<dim3(16, 16, 2), dim3(32, 8), 0, stream>>>(W1, Wg, W1t, Wgt);

    // 3) h = PReLU(BN(text@W1 + b1))   [fp32 A inline-cvt, bf16 out]
    k_gemm_mfma<1><<<1024, 256, 0, stream>>>(text, W1t, h_bf, b1, gamma, beta, rmean, rvar, alpha1, nullptr);

    // 4) xws = (h@Wg) * dinv[row]     [bf16 out]
    k_gemm_mfma<2><<<1024, 256, 0, stream>>>(h_bf, Wgt, xws, nullptr, nullptr, nullptr, nullptr, nullptr, nullptr, dinv);

    // 5) fused gather + epilogue + L2 norm + residual
    k_gather_final<<<NN / 4, 256, 0, stream>>>(offs, csr, xws, dinv, bg, alpha2, text, out);
}

// Round 8
// 149.167 us; speedup vs baseline: 15.4313x; 1.0201x over previous
//
#include <hip/hip_runtime.h>
#include <math.h>

#define DD    512
#define NN    32768      // B*L nodes
#define EE    262144     // edges (without self loops)

typedef float f32x4 __attribute__((ext_vector_type(4)));
typedef __bf16 bf16x8 __attribute__((ext_vector_type(8)));
typedef __bf16 bf16x4 __attribute__((ext_vector_type(4)));

// ---------------- CSR build ----------------
__global__ void k_zero(int* __restrict__ cnt) {
    int i = blockIdx.x * 256 + threadIdx.x;
    if (i < NN) cnt[i] = 0;
}

__global__ void k_count(const int* __restrict__ dst, int* __restrict__ cnt) {
    int e = blockIdx.x * 256 + threadIdx.x;
    if (e < EE) atomicAdd(&cnt[dst[e]], 1);
}

__global__ __launch_bounds__(1024) void k_scan(
    const int* __restrict__ cnt, int* __restrict__ offs,
    int* __restrict__ cursor, float* __restrict__ dinv)
{
    __shared__ int part[1024];
    int t = threadIdx.x;
    int base = t * 32;
    int local[32];
    int s = 0;
#pragma unroll
    for (int i = 0; i < 32; ++i) { local[i] = s; s += cnt[base + i]; }
    part[t] = s;
    __syncthreads();
    for (int off = 1; off < 1024; off <<= 1) {
        int v = (t >= off) ? part[t - off] : 0;
        __syncthreads();
        part[t] += v;
        __syncthreads();
    }
    int prev = (t == 0) ? 0 : part[t - 1];
#pragma unroll
    for (int i = 0; i < 32; ++i) {
        int o = prev + local[i];
        offs[base + i] = o;
        cursor[base + i] = o;
        dinv[base + i] = rsqrtf((float)cnt[base + i] + 1.0f);
    }
    if (t == 1023) offs[NN] = part[1023];
}

__global__ void k_fill(const int* __restrict__ src, const int* __restrict__ dst,
                       int* __restrict__ cursor, int* __restrict__ csr) {
    int e = blockIdx.x * 256 + threadIdx.x;
    if (e < EE) {
        int d = dst[e];
        int p = atomicAdd(&cursor[d], 1);
        csr[p] = src[e];
    }
}

// ---------------- weight transpose + convert: Wt[n][k] = (bf16)W[k][n] ----------------
__global__ __launch_bounds__(256) void k_wt(const float* __restrict__ W1, const float* __restrict__ Wg,
                                            __bf16* __restrict__ W1t, __bf16* __restrict__ Wgt) {
    __shared__ float tile[32][33];
    const float* W = blockIdx.z ? Wg : W1;
    __bf16* Wt = blockIdx.z ? Wgt : W1t;
    int x0 = blockIdx.x * 32;   // n block
    int y0 = blockIdx.y * 32;   // k block
    int tx = threadIdx.x;       // 0..31
    for (int j = threadIdx.y; j < 32; j += 8)
        tile[j][tx] = W[(size_t)(y0 + j) * DD + x0 + tx];
    __syncthreads();
    for (int j = threadIdx.y; j < 32; j += 8)
        Wt[(size_t)(x0 + j) * DD + y0 + tx] = (__bf16)tile[tx][j];
}

// ---------------- bf16 MFMA GEMM, 128x128 tile, BK=32, counted-vmcnt pipeline (T4) ----------------
// MODE 1: A fp32 (text), reg-staged + inline cvt; out = PReLU(BN(A@B+b1)) bf16
// MODE 2: A bf16 (h), global_load_lds;            out = (A@B)*dinv[row]  bf16
// K-loop sync: raw s_barrier + counted s_waitcnt vmcnt(N) (never 0 mid-loop) so
// next-tile staging loads stay in flight across barriers (AITER/HK pattern).
// Grid: 1D 1024, XCD-affinity swizzle (same-panel n-tiles on same XCD for L2 A-reuse).
template <int MODE>
__global__ __launch_bounds__(256) void k_gemm_mfma(
    const void* __restrict__ Ap,
    const __bf16* __restrict__ Bt,
    __bf16* __restrict__ Cout,
    const float* __restrict__ bias,
    const float* __restrict__ gamma, const float* __restrict__ beta,
    const float* __restrict__ mean, const float* __restrict__ var,
    const float* __restrict__ alphap,
    const float* __restrict__ dinv)
{
    __shared__ __bf16 As[2][128 * 32];
    __shared__ __bf16 Bs[2][128 * 32];

    const int tid  = threadIdx.x;
    const int lane = tid & 63;
    const int w    = tid >> 6;
    const int wm   = (w >> 1) * 64;
    const int wn   = (w & 1) * 64;
    const int work = ((blockIdx.x & 7) << 7) + (blockIdx.x >> 3);  // bijective, 1024
    const int m0   = (work >> 2) * 128;
    const int n0   = (work & 3) * 128;

    f32x4 acc[4][4] = {};
    float4 fa[2][2];   // MODE1 A-staging registers

    auto stageB = [&](int bb, int k0) {
#pragma unroll
        for (int rd = 0; rd < 2; ++rd) {
            int cbase = rd * 256 + w * 64;
            int cidx = cbase + lane;
            int r = cidx >> 2, s = cidx & 3;
            int c = s ^ ((r >> 1) & 3);
            const __bf16* gb = Bt + (size_t)(n0 + r) * DD + k0 + c * 8;
            __builtin_amdgcn_global_load_lds(
                (const __attribute__((address_space(1))) unsigned int*)gb,
                (__attribute__((address_space(3))) unsigned int*)(&Bs[bb][cbase * 8]), 16, 0, 0);
        }
    };
    auto stageA_lds = [&](int bb, int k0) {
        const __bf16* A = (const __bf16*)Ap;
#pragma unroll
        for (int rd = 0; rd < 2; ++rd) {
            int cbase = rd * 256 + w * 64;
            int cidx = cbase + lane;
            int r = cidx >> 2, s = cidx & 3;
            int c = s ^ ((r >> 1) & 3);
            const __bf16* ga = A + (size_t)(m0 + r) * DD + k0 + c * 8;
            __builtin_amdgcn_global_load_lds(
                (const __attribute__((address_space(1))) unsigned int*)ga,
                (__attribute__((address_space(3))) unsigned int*)(&As[bb][cbase * 8]), 16, 0, 0);
        }
    };
    auto loadA = [&](int k0) {
        const float* A = (const float*)Ap;
#pragma unroll
        for (int hh = 0; hh < 2; ++hh) {
            int ci = tid + hh * 256;
            int r = ci >> 2, s = ci & 3;
            int c = s ^ ((r >> 1) & 3);
            const float* ga = A + (size_t)(m0 + r) * DD + k0 + c * 8;
            fa[hh][0] = *(const float4*)ga;
            fa[hh][1] = *(const float4*)(ga + 4);
        }
    };
    auto writeA = [&](int bb) {
#pragma unroll
        for (int hh = 0; hh < 2; ++hh) {
            int ci = tid + hh * 256;
            bf16x8 o;
            o[0] = (__bf16)fa[hh][0].x; o[1] = (__bf16)fa[hh][0].y;
            o[2] = (__bf16)fa[hh][0].z; o[3] = (__bf16)fa[hh][0].w;
            o[4] = (__bf16)fa[hh][1].x; o[5] = (__bf16)fa[hh][1].y;
            o[6] = (__bf16)fa[hh][1].z; o[7] = (__bf16)fa[hh][1].w;
            *(bf16x8*)&As[bb][ci * 8] = o;
        }
    };

    // --- prologue: tile 0 into buffer 0 ---
    if constexpr (MODE == 1) {
        loadA(0);
        stageB(0, 0);
        writeA(0);                                    // compiler waits fa's vmcnt
        asm volatile("s_waitcnt lgkmcnt(0)" ::: "memory");   // ds_writes visible
    } else {
        stageA_lds(0, 0);
        stageB(0, 0);
    }

    // --- K loop: 16 steps, fully unrolled; 2 raw barriers/step, counted vmcnt ---
#pragma unroll
    for (int kt = 0; kt < 16; ++kt) {
        const int cur = kt & 1;
        const int nxt = cur ^ 1;
        const int k1  = (kt + 1) * 32;

        // 1) issue next tile's staging (stays in flight across barriers)
        if (kt < 15) {
            if constexpr (MODE == 1) { loadA(k1); stageB(nxt, k1); }
            else                     { stageA_lds(nxt, k1); stageB(nxt, k1); }
        }

        // 2) wait ONLY current tile's staging loads (oldest), then barrier
        if constexpr (MODE == 1) {
            if (kt < 15) asm volatile("s_waitcnt vmcnt(6)" ::: "memory");
            else         asm volatile("s_waitcnt vmcnt(0)" ::: "memory");
        } else {
            if (kt < 15) asm volatile("s_waitcnt vmcnt(4)" ::: "memory");
            else         asm volatile("s_waitcnt vmcnt(0)" ::: "memory");
        }
        __builtin_amdgcn_s_barrier();                 // B1: cur tile ready for all waves
        asm volatile("" ::: "memory");

        // 3) frags of current tile
        bf16x8 af[4], bfr[4];
#pragma unroll
        for (int m = 0; m < 4; ++m) {
            int r = wm + m * 16 + (lane & 15);
            int s = (lane >> 4) ^ ((r >> 1) & 3);
            af[m] = *(const bf16x8*)&As[cur][r * 32 + s * 8];
            int q = wn + m * 16 + (lane & 15);
            int sq = (lane >> 4) ^ ((q >> 1) & 3);
            bfr[m] = *(const bf16x8*)&Bs[cur][q * 32 + sq * 8];
        }

        // 4) compute
#pragma unroll
        for (int m = 0; m < 4; ++m)
#pragma unroll
            for (int n = 0; n < 4; ++n)
                acc[m][n] = __builtin_amdgcn_mfma_f32_16x16x32_bf16(af[m], bfr[n], acc[m][n], 0, 0, 0);

        // 5) MODE1: convert+write next A regs into next buffer, drain ds_writes
        if constexpr (MODE == 1) {
            if (kt < 15) writeA(nxt);
            asm volatile("s_waitcnt lgkmcnt(0)" ::: "memory");
        }

        // 6) B2: all waves done reading cur buffer -> next region may overwrite it
        asm volatile("" ::: "memory");
        __builtin_amdgcn_s_barrier();
        asm volatile("" ::: "memory");
    }

    // --- epilogue: C/D layout col = lane&15, row = (lane>>4)*4 + j ---
    float alpha = (MODE == 1) ? alphap[0] : 0.0f;
#pragma unroll
    for (int m = 0; m < 4; ++m) {
        int row_base = m0 + wm + m * 16 + ((lane >> 4) << 2);
#pragma unroll
        for (int n = 0; n < 4; ++n) {
            int col = n0 + wn + n * 16 + (lane & 15);
#pragma unroll
            for (int j = 0; j < 4; ++j) {
                int row = row_base + j;
                float x = acc[m][n][j];
                if (MODE == 1) {
                    x += bias[col];
                    x = (x - mean[col]) * rsqrtf(var[col] + 1e-5f) * gamma[col] + beta[col];
                    x = (x >= 0.0f) ? x : alpha * x;
                } else {
                    x *= dinv[row];
                }
                Cout[(size_t)row * DD + col] = (__bf16)x;
            }
        }
    }
}

// ---------------- fused gather + dinv + bias + PReLU + L2 norm + residual ----------------
__global__ __launch_bounds__(256) void k_gather_final(
    const int* __restrict__ offs, const int* __restrict__ csr,
    const __bf16* __restrict__ xws, const float* __restrict__ dinv,
    const float* __restrict__ bg, const float* __restrict__ alpha2,
    const float* __restrict__ text, float* __restrict__ out)
{
    int blk = blockIdx.x;                              // 0..8191
    int sb  = ((blk & 7) << 10) + (blk >> 3);          // XCD-chunked (bijective)
    int wave = threadIdx.x >> 6;
    int lane = threadIdx.x & 63;
    int node = sb * 4 + wave;
    int c = lane * 8;
    int beg = offs[node], end = offs[node + 1];
    int ne = end - beg;

    bf16x8 sv = *(const bf16x8*)(xws + (size_t)node * DD + c);   // self loop
    float a[8];
#pragma unroll
    for (int i = 0; i < 8; ++i) a[i] = (float)sv[i];

    int k = 0;
    for (; k + 4 <= ne; k += 4) {
        int s0 = csr[beg + k + 0];
        int s1 = csr[beg + k + 1];
        int s2 = csr[beg + k + 2];
        int s3 = csr[beg + k + 3];
        bf16x8 v0 = *(const bf16x8*)(xws + (size_t)s0 * DD + c);
        bf16x8 v1 = *(const bf16x8*)(xws + (size_t)s1 * DD + c);
        bf16x8 v2 = *(const bf16x8*)(xws + (size_t)s2 * DD + c);
        bf16x8 v3 = *(const bf16x8*)(xws + (size_t)s3 * DD + c);
#pragma unroll
        for (int i = 0; i < 8; ++i)
            a[i] += (float)v0[i] + (float)v1[i] + (float)v2[i] + (float)v3[i];
    }
    for (; k < ne; ++k) {
        int s = csr[beg + k];
        bf16x8 v = *(const bf16x8*)(xws + (size_t)s * DD + c);
#pragma unroll
        for (int i = 0; i < 8; ++i) a[i] += (float)v[i];
    }

    float di = dinv[node];
    float al = alpha2[0];
    float g[8];
    float ss = 0.0f;
#pragma unroll
    for (int i = 0; i < 8; ++i) {
        float x = a[i] * di + bg[c + i];
        x = (x >= 0.0f) ? x : al * x;
        g[i] = x;
        ss += x * x;
    }
#pragma unroll
    for (int off = 1; off < 64; off <<= 1) ss += __shfl_xor(ss, off, 64);
    float inv = 1.0f / fmaxf(sqrtf(ss), 1e-12f);

    float4 t0 = *(const float4*)(text + (size_t)node * DD + c);
    float4 t1 = *(const float4*)(text + (size_t)node * DD + c + 4);
    float4 o0, o1;
    o0.x = g[0] * inv + t0.x; o0.y = g[1] * inv + t0.y;
    o0.z = g[2] * inv + t0.z; o0.w = g[3] * inv + t0.w;
    o1.x = g[4] * inv + t1.x; o1.y = g[5] * inv + t1.y;
    o1.z = g[6] * inv + t1.z; o1.w = g[7] * inv + t1.w;
    *(float4*)(out + (size_t)node * DD + c)     = o0;
    *(float4*)(out + (size_t)node * DD + c + 4) = o1;
}

extern "C" void kernel_launch(void* const* d_in, const int* in_sizes, int n_in,
                              void* d_out, int out_size, void* d_ws, size_t ws_size,
                              hipStream_t stream) {
    const float* text   = (const float*)d_in[0];
    const int*   esrc   = (const int*)d_in[1];
    const int*   edst   = (const int*)d_in[2];
    const float* W1     = (const float*)d_in[3];
    const float* b1     = (const float*)d_in[4];
    const float* gamma  = (const float*)d_in[5];
    const float* beta   = (const float*)d_in[6];
    const float* rmean  = (const float*)d_in[7];
    const float* rvar   = (const float*)d_in[8];
    const float* alpha1 = (const float*)d_in[9];
    const float* Wg     = (const float*)d_in[10];
    const float* bg     = (const float*)d_in[11];
    const float* alpha2 = (const float*)d_in[12];
    float* out = (float*)d_out;

    // workspace layout (~66.5 MiB)
    char* p = (char*)d_ws;
    auto alloc = [&](size_t bytes) { char* r = p; p += (bytes + 255) & ~(size_t)255; return r; };
    int*    cnt     = (int*)alloc((size_t)NN * 4);
    int*    offs    = (int*)alloc((size_t)(NN + 1) * 4);
    int*    cursor  = (int*)alloc((size_t)NN * 4);
    float*  dinv    = (float*)alloc((size_t)NN * 4);
    int*    csr     = (int*)alloc((size_t)EE * 4);
    __bf16* W1t     = (__bf16*)alloc((size_t)DD * DD * 2);
    __bf16* Wgt     = (__bf16*)alloc((size_t)DD * DD * 2);
    __bf16* h_bf    = (__bf16*)alloc((size_t)NN * DD * 2);
    __bf16* xws     = (__bf16*)alloc((size_t)NN * DD * 2);

    // 1) CSR build + dinv
    k_zero<<<NN / 256, 256, 0, stream>>>(cnt);
    k_count<<<EE / 256, 256, 0, stream>>>(edst, cnt);
    k_scan<<<1, 1024, 0, stream>>>(cnt, offs, cursor, dinv);
    k_fill<<<EE / 256, 256, 0, stream>>>(esrc, edst, cursor, csr);

    // 2) weights -> bf16 [n][k]
    k_wt<<<dim3(16, 16, 2), dim3(32, 8), 0, stream>>>(W1, Wg, W1t, Wgt);

    // 3) h = PReLU(BN(text@W1 + b1))   [fp32 A inline-cvt, bf16 out]
    k_gemm_mfma<1><<<1024, 256, 0, stream>>>(text, W1t, h_bf, b1, gamma, beta, rmean, rvar, alpha1, nullptr);

    // 4) xws = (h@Wg) * dinv[row]     [bf16 out]
    k_gemm_mfma<2><<<1024, 256, 0, stream>>>(h_bf, Wgt, xws, nullptr, nullptr, nullptr, nullptr, nullptr, nullptr, dinv);

    // 5) fused gather + epilogue + L2 norm + residual
    k_gather_final<<<NN / 4, 256, 0, stream>>>(offs, csr, xws, dinv, bg, alpha2, text, out);
}